// Round 1
// baseline (4144.336 us; speedup 1.0000x reference)
//
#include <hip/hip_runtime.h>

// ---------------- problem constants ----------------
#define BB 8
#define CC 256
#define TT 256
#define FF 128
#define DD 64
#define HH 128
#define NHEADS 4
#define KK 8
#define II 512            // D*K
#define P1 32768          // T*F
#define T2 128
#define F2 64
#define P2 8192
#define T4 64
#define F4 32
#define P4 2048           // T4*F4

// freq pathway: N=512 seqs, L=25 ; time pathway: N=256 seqs, L=57
#define LF 25
#define LT 57
#define MF (512*LF)       // 12800
#define MT (256*LT)       // 14592

// ---------------- generic f32 tiled GEMM ----------------
// C[row][n] = sum_k A'[row][k] * B[k][n]  (+bias)(+resid), 64x64 tile, BK=32.
// a_mode: 0 A row-major [row*Kd+k] (+bb*sA)
//         1 A = src[(b2*Kd + k)*2048 + r], b2=row>>11, r=row&2047 (batched transpose, aR==2048)
//         2 convT gather: f=row%aR, tap=k>>9, i=k&511, l=f+tap-7; A=z[((row/aR)*convL+l)*512+i] or 0
// c_mode: 0 ci = bb*sC + row*N + n
//         1 ci = (b2*N + n)*cR + r           (channel-major per batch)
//         2 ci = (b2*N + n)*cR + ff*(cR/cF) + tt   (channel-major, spatial transpose)
__global__ __launch_bounds__(256) void gemm_k(
    const float* __restrict__ A, const float* __restrict__ Bm, float* __restrict__ Cm,
    const float* __restrict__ bias, const float* __restrict__ resid,
    int M, int N, int Kd,
    long long sA, long long sB, long long sC,
    int bias_mode, int a_mode, int aR, int convL,
    int c_mode, int cR, int cF)
{
    __shared__ float As[32][66];
    __shared__ float Bs[32][64];
    int bb = blockIdx.z;
    int m0 = blockIdx.y * 64, n0 = blockIdx.x * 64;
    int tid = threadIdx.x;
    int tn = tid & 15, tm = tid >> 4;

    float acc[4][4];
#pragma unroll
    for (int i = 0; i < 4; ++i)
#pragma unroll
        for (int j = 0; j < 4; ++j) acc[i][j] = 0.f;

    const float* Ab = A + (long long)bb * sA;
    const float* Bb = Bm + (long long)bb * sB;

    // precompute per-thread A staging bases
    long long abase[8]; int fo[8];
    if (a_mode == 1) {
        int mm = tid & 63; int row = m0 + mm;
        int b2 = row >> 11; int r = row & 2047;
        abase[0] = ((long long)b2 * Kd) * 2048 + r;
    } else if (a_mode == 0) {
#pragma unroll
        for (int j = 0; j < 8; ++j) {
            int mm = (tid >> 5) + 8 * j;
            abase[j] = (long long)(m0 + mm) * Kd;
        }
    } else {
#pragma unroll
        for (int j = 0; j < 8; ++j) {
            int mm = (tid >> 5) + 8 * j;
            int row = m0 + mm;
            fo[j] = row % aR;
            abase[j] = (long long)(row / aR) * convL;
        }
    }
    int nn_b = tid & 63;

    for (int k0 = 0; k0 < Kd; k0 += 32) {
        // stage A
        if (a_mode == 1) {
            int mm = tid & 63;
#pragma unroll
            for (int j = 0; j < 8; ++j) {
                int kk = (tid >> 6) + 4 * j;
                As[kk][mm] = A[abase[0] + (long long)(k0 + kk) * 2048];
            }
        } else if (a_mode == 0) {
            int kk = tid & 31;
#pragma unroll
            for (int j = 0; j < 8; ++j) {
                int mm = (tid >> 5) + 8 * j;
                As[kk][mm] = Ab[abase[j] + k0 + kk];
            }
        } else {
            int kk = tid & 31;
            int kg = k0 + kk;
            int tap = kg >> 9, ii = kg & 511;
#pragma unroll
            for (int j = 0; j < 8; ++j) {
                int mm = (tid >> 5) + 8 * j;
                int l = fo[j] + tap - 7;
                As[kk][mm] = (l >= 0 && l < convL) ? A[(abase[j] + l) * 512 + ii] : 0.f;
            }
        }
        // stage B
#pragma unroll
        for (int j = 0; j < 8; ++j) {
            int kk = (tid >> 6) + 4 * j;
            Bs[kk][nn_b] = Bb[(long long)(k0 + kk) * N + (n0 + nn_b)];
        }
        __syncthreads();
#pragma unroll
        for (int kk = 0; kk < 32; ++kk) {
            float av[4], bv[4];
#pragma unroll
            for (int x = 0; x < 4; ++x) av[x] = As[kk][tm * 4 + x];
#pragma unroll
            for (int y = 0; y < 4; ++y) bv[y] = Bs[kk][tn * 4 + y];
#pragma unroll
            for (int x = 0; x < 4; ++x)
#pragma unroll
                for (int y = 0; y < 4; ++y) acc[x][y] += av[x] * bv[y];
        }
        __syncthreads();
    }

#pragma unroll
    for (int x = 0; x < 4; ++x) {
        int row = m0 + tm * 4 + x;
#pragma unroll
        for (int y = 0; y < 4; ++y) {
            int n = n0 + tn * 4 + y;
            float v = acc[x][y];
            if (bias_mode == 1) v += bias[row];
            else if (bias_mode == 2) v += bias[n];
            long long ci;
            if (c_mode == 0) ci = (long long)bb * sC + (long long)row * N + n;
            else if (c_mode == 1) {
                int b2 = row / cR, r = row - b2 * cR;
                ci = ((long long)b2 * N + n) * cR + r;
            } else {
                int b2 = row / cR, r = row - b2 * cR;
                int tt = r / cF, ff = r - tt * cF;
                ci = ((long long)b2 * N + n) * cR + (long long)ff * (cR / cF) + tt;
            }
            if (resid) v += resid[ci];
            Cm[ci] = v;
        }
    }
}

// ---------------- 3x3 stride2 pad1 conv + ReLU ----------------
__global__ void down_k(const float* __restrict__ in, const float* __restrict__ w,
                       const float* __restrict__ bias, float* __restrict__ out,
                       int Hi, int Wi)
{
    int Ho = Hi >> 1, Wo = Wi >> 1;
    long long gid = (long long)blockIdx.x * blockDim.x + threadIdx.x;
    long long total = (long long)BB * DD * Ho * Wo;
    if (gid >= total) return;
    int x = (int)(gid % Wo); long long t1 = gid / Wo;
    int y = (int)(t1 % Ho); long long t2 = t1 / Ho;
    int d = (int)(t2 & 63); int b = (int)(t2 >> 6);
    float acc = bias[d];
    const float* ip = in + (long long)b * DD * Hi * Wi;
    const float* wp = w + d * DD * 9;
    for (int c = 0; c < DD; ++c) {
        const float* icp = ip + (long long)c * Hi * Wi;
        const float* wcp = wp + c * 9;
#pragma unroll
        for (int kh = 0; kh < 3; ++kh) {
            int iy = 2 * y - 1 + kh;
            if (iy < 0 || iy >= Hi) continue;
            const float* irp = icp + (long long)iy * Wi;
#pragma unroll
            for (int kw = 0; kw < 3; ++kw) {
                int ix = 2 * x - 1 + kw;
                if (ix < 0 || ix >= Wi) continue;
                acc += irp[ix] * wcp[kh * 3 + kw];
            }
        }
    }
    out[gid] = fmaxf(acc, 0.f);
}

// ---------------- unfolds (build u = im2col of ag along scan axis) ----------------
__global__ void unfold_freq_k(const float* __restrict__ ag, float* __restrict__ u)
{
    long long gid = (long long)blockIdx.x * blockDim.x + threadIdx.x;
    if (gid >= (long long)MF * II) return;
    int ch = (int)(gid & 511); int row = (int)(gid >> 9);
    int b = row / (T4 * LF); int rem = row - b * (T4 * LF);
    int t = rem / LF; int l = rem - t * LF;
    int d = ch >> 3, i = ch & 7;
    u[gid] = ag[((long long)((b * DD + d) * T4 + t)) * F4 + l + i];
}
__global__ void unfold_time_k(const float* __restrict__ ag, float* __restrict__ u)
{
    long long gid = (long long)blockIdx.x * blockDim.x + threadIdx.x;
    if (gid >= (long long)MT * II) return;
    int ch = (int)(gid & 511); int row = (int)(gid >> 9);
    int b = row / (F4 * LT); int rem = row - b * (F4 * LT);
    int tt = rem / LT; int l = rem - tt * LT;
    int d = ch >> 3, i = ch & 7;
    u[gid] = ag[((long long)((b * DD + d) * T4 + (l + i))) * F4 + tt];
}

// ---------------- weight packing ----------------
// Wcat[k][0:384]=Wx[0], [384:512]=Whw[0], [512:896]=Wx[1], [896:1024]=Whw[1]
__global__ void pack_wcat_k(const float* __restrict__ Wx, const float* __restrict__ Whw,
                            float* __restrict__ Wcat)
{
    int gid = blockIdx.x * blockDim.x + threadIdx.x;
    if (gid >= 512 * 1024) return;
    int col = gid & 1023; int k = gid >> 10;
    int dir = col >> 9; int c = col & 511;
    float v;
    if (c < 384) v = Wx[(dir * 512 + k) * 384 + c];
    else         v = Whw[(dir * 512 + k) * 128 + (c - 384)];
    Wcat[gid] = v;
}
// Wct[tap*512+i][d] = ctw[d][i][0][tap]
__global__ void pack_wct_k(const float* __restrict__ ctw, float* __restrict__ Wct)
{
    int gid = blockIdx.x * blockDim.x + threadIdx.x;
    if (gid >= 4096 * 64) return;
    int d = gid & 63; int kk = gid >> 6;
    int tap = kk >> 9, i = kk & 511;
    Wct[gid] = ctw[((d * 512) + i) * 8 + tap];
}

// ---------------- SRU elementwise recurrence ----------------
// G rows: [xt(0:128) fp(128:256) rp(256:384) xhw(384:512) | dir1: +512]
__global__ void sru_scan_k(const float* __restrict__ G, const float* __restrict__ bfw,
                           const float* __restrict__ brw, float* __restrict__ hout,
                           int Nn, int L)
{
    int gid = blockIdx.x * blockDim.x + threadIdx.x;
    if (gid >= Nn * 256) return;
    int h = gid & 127; int dir = (gid >> 7) & 1; int n = gid >> 8;
    const float bf = bfw[dir * 128 + h], br = brw[dir * 128 + h];
    int base = dir * 512 + h;
    float c = 0.f;
    for (int s = 0; s < L; ++s) {
        int l = dir ? (L - 1 - s) : s;
        const float* g = G + ((long long)(n * L + l)) * 1024 + base;
        float xt = g[0];
        float fv = 1.f / (1.f + __expf(-(g[128] + bf)));
        float rv = 1.f / (1.f + __expf(-(g[256] + br)));
        float xh = g[384];
        c = fv * c + (1.f - fv) * xt;
        float hv = rv * c + (1.f - rv) * xh;
        hout[((long long)(n * L + l)) * 256 + dir * 128 + h] = hv;
    }
}

// ---------------- flash attention (dh=16, 4 heads) ----------------
__global__ __launch_bounds__(256) void attn_k(const float* __restrict__ qkv, float* __restrict__ out)
{
    int mtile = blockIdx.x, head = blockIdx.y, b = blockIdx.z;
    int tid = threadIdx.x;
    int qi = tid & 63, quad = tid >> 6;
    int m = mtile * 64 + qi;
    const float* qrow = qkv + ((long long)(b * P4 + m)) * 192 + head * 16;
    float q[16];
#pragma unroll
    for (int d = 0; d < 16; ++d) q[d] = qrow[d] * 0.25f;  // 1/sqrt(16)
    __shared__ float Ks[64][16];
    __shared__ float Vs[64][16];
    __shared__ float red[64 * 4 * 18];
    float mmax = -1e30f, lsum = 0.f, acc[16];
#pragma unroll
    for (int d = 0; d < 16; ++d) acc[d] = 0.f;

    for (int j0 = 0; j0 < P4; j0 += 64) {
        __syncthreads();
        for (int e = tid; e < 1024; e += 256) {
            int key = e >> 4, dd = e & 15;
            long long basei = ((long long)(b * P4 + j0 + key)) * 192 + head * 16;
            Ks[key][dd] = qkv[basei + 64 + dd];
            Vs[key][dd] = qkv[basei + 128 + dd];
        }
        __syncthreads();
        for (int jj = quad; jj < 64; jj += 4) {
            float s = 0.f;
#pragma unroll
            for (int d = 0; d < 16; ++d) s += q[d] * Ks[jj][d];
            float nm = fmaxf(mmax, s);
            float corr = __expf(mmax - nm);
            float pj = __expf(s - nm);
            lsum = lsum * corr + pj;
#pragma unroll
            for (int d = 0; d < 16; ++d) acc[d] = acc[d] * corr + pj * Vs[jj][d];
            mmax = nm;
        }
    }
    __syncthreads();
    float* slot = red + (qi * 4 + quad) * 18;
    slot[0] = mmax; slot[1] = lsum;
#pragma unroll
    for (int d = 0; d < 16; ++d) slot[2 + d] = acc[d];
    __syncthreads();
    if (quad == 0) {
        float M = -1e30f;
        for (int t = 0; t < 4; ++t) M = fmaxf(M, red[(qi * 4 + t) * 18]);
        float L = 0.f; float o[16];
#pragma unroll
        for (int d = 0; d < 16; ++d) o[d] = 0.f;
        for (int t = 0; t < 4; ++t) {
            float* sl = red + (qi * 4 + t) * 18;
            float w = __expf(sl[0] - M);
            L += sl[1] * w;
#pragma unroll
            for (int d = 0; d < 16; ++d) o[d] += sl[2 + d] * w;
        }
        float inv = 1.f / L;
        float* op = out + ((long long)(b * P4 + m)) * 64 + head * 16;
#pragma unroll
        for (int d = 0; d < 16; ++d) op[d] = o[d] * inv;
    }
}

// ---------------- convT k=2 s=2 (exactly one tap per output) + residual ----------------
__global__ void up_k(const float* __restrict__ in, const float* __restrict__ w,
                     const float* __restrict__ bias, const float* __restrict__ resid,
                     float* __restrict__ out, int Hi, int Wi)
{
    int Ho = Hi * 2, Wo = Wi * 2;
    long long gid = (long long)blockIdx.x * blockDim.x + threadIdx.x;
    long long total = (long long)BB * DD * Ho * Wo;
    if (gid >= total) return;
    int x = (int)(gid % Wo); long long t1 = gid / Wo;
    int y = (int)(t1 % Ho); long long t2 = t1 / Ho;
    int d = (int)(t2 & 63); int b = (int)(t2 >> 6);
    int kh = 1 - (y & 1), kw = 1 - (x & 1);   // JAX conv_transpose: no kernel flip
    int iy = y >> 1, ix = x >> 1;
    float acc = bias[d];
    const float* ip = in + (long long)b * DD * Hi * Wi + (long long)iy * Wi + ix;
    const float* wp = w + d * DD * 4 + kh * 2 + kw;
    for (int c = 0; c < DD; ++c) acc += ip[(long long)c * Hi * Wi] * wp[c * 4];
    out[gid] = acc + resid[gid];
}

// ---------------- host launch ----------------
extern "C" void kernel_launch(void* const* d_in, const int* in_sizes, int n_in,
                              void* d_out, int out_size, void* d_ws, size_t ws_size,
                              hipStream_t stream)
{
    const float* A_in  = (const float*)d_in[0];
    const float* cw    = (const float*)d_in[1];
    const float* cb    = (const float*)d_in[2];
    const float* dw0   = (const float*)d_in[3];
    const float* db0   = (const float*)d_in[4];
    const float* dw1   = (const float*)d_in[5];
    const float* db1   = (const float*)d_in[6];
    const float* f_Wx  = (const float*)d_in[7];
    const float* f_bf  = (const float*)d_in[8];
    const float* f_br  = (const float*)d_in[9];
    const float* f_Whw = (const float*)d_in[10];
    const float* f_pw  = (const float*)d_in[11];
    const float* f_pb  = (const float*)d_in[12];
    const float* f_ctw = (const float*)d_in[13];
    const float* f_ctb = (const float*)d_in[14];
    const float* t_Wx  = (const float*)d_in[15];
    const float* t_bf  = (const float*)d_in[16];
    const float* t_br  = (const float*)d_in[17];
    const float* t_Whw = (const float*)d_in[18];
    const float* t_pw  = (const float*)d_in[19];
    const float* t_pb  = (const float*)d_in[20];
    const float* t_ctw = (const float*)d_in[21];
    const float* t_ctb = (const float*)d_in[22];
    const float* qkv_w = (const float*)d_in[23];
    const float* qkv_b = (const float*)d_in[24];
    const float* ow    = (const float*)d_in[25];
    const float* ob    = (const float*)d_in[26];
    const float* upw0  = (const float*)d_in[27];
    const float* upb0  = (const float*)d_in[28];
    const float* upw1  = (const float*)d_in[29];
    const float* upb1  = (const float*)d_in[30];
    const float* fw    = (const float*)d_in[31];
    const float* fb    = (const float*)d_in[32];

    float* ws  = (float*)d_ws;
    float* out = (float*)d_out;

    // workspace layout (floats)
    float* ag   = ws + 0;          // 1,048,576
    float* x1   = ws + 1048576;    // 4,194,304
    float* u    = ws + 5242880;    // 7,471,104 (later reused as y1)
    float* G    = ws + 12713984;   // 14,942,208 (later reused as y0, spills into h)
    float* hbuf = ws + 27656192;   // 3,735,552
    float* z    = ws + 31391744;   // 7,471,104
    float* Wcat = ws + 38862848;   // 524,288
    float* Wct  = ws + 39387136;   // 262,144
    float* fout = ws + 39649280;   // 1,048,576
    float* tout = ws + 40697856;   // 1,048,576
    float* qkvb = ws + 41746432;   // 3,145,728
    float* attn = ws + 44892160;   // 1,048,576
    float* dp   = ws + 45940736;   // 1,048,576  (total 46,989,312 floats ≈ 180 MiB)
    float* y1 = u;
    float* y0 = G;
    float* x0 = out;               // x0 parked in d_out (final conv reads only y0)

    dim3 blk(256);

    // 1. compress: per-b GEMM  x0[d][p] = cw[d][c] * A[c][p] + cb[d]
    gemm_k<<<dim3(512, 1, 8), blk, 0, stream>>>(cw, A_in, x0, cb, nullptr,
        64, 32768, 256, 0LL, 8388608LL, 2097152LL, 1, 0, 0, 0, 0, 0, 0);

    // 2-3. downsample
    down_k<<<dim3(4194304 / 256), blk, 0, stream>>>(x0, dw0, db0, x1, TT, FF);
    down_k<<<dim3(1048576 / 256), blk, 0, stream>>>(x1, dw1, db1, ag, T2, F2);

    // ---- frequency pathway ----
    unfold_freq_k<<<dim3((MF * II) / 256), blk, 0, stream>>>(ag, u);
    pack_wcat_k<<<dim3(524288 / 256), blk, 0, stream>>>(f_Wx, f_Whw, Wcat);
    gemm_k<<<dim3(16, MF / 64, 1), blk, 0, stream>>>(u, Wcat, G, nullptr, nullptr,
        MF, 1024, 512, 0LL, 0LL, 0LL, 0, 0, 0, 0, 0, 0, 0);
    sru_scan_k<<<dim3(131072 / 256), blk, 0, stream>>>(G, f_bf, f_br, hbuf, 512, LF);
    gemm_k<<<dim3(8, MF / 64, 1), blk, 0, stream>>>(hbuf, f_pw, z, f_pb, nullptr,
        MF, 512, 256, 0LL, 0LL, 0LL, 2, 0, 0, 0, 0, 0, 0);
    pack_wct_k<<<dim3(262144 / 256), blk, 0, stream>>>(f_ctw, Wct);
    // convT(1,8) as GEMM K=4096; write (B,D,64,32), + ag residual, + ctb
    gemm_k<<<dim3(1, 256, 1), blk, 0, stream>>>(z, Wct, fout, f_ctb, ag,
        16384, 64, 4096, 0LL, 0LL, 0LL, 2, 2, 32, LF, 1, 2048, 0);

    // ---- time pathway ----
    unfold_time_k<<<dim3((MT * II) / 256), blk, 0, stream>>>(ag, u);
    pack_wcat_k<<<dim3(524288 / 256), blk, 0, stream>>>(t_Wx, t_Whw, Wcat);
    gemm_k<<<dim3(16, MT / 64, 1), blk, 0, stream>>>(u, Wcat, G, nullptr, nullptr,
        MT, 1024, 512, 0LL, 0LL, 0LL, 0, 0, 0, 0, 0, 0, 0);
    sru_scan_k<<<dim3(65536 / 256), blk, 0, stream>>>(G, t_bf, t_br, hbuf, 256, LT);
    gemm_k<<<dim3(8, MT / 64, 1), blk, 0, stream>>>(hbuf, t_pw, z, t_pb, nullptr,
        MT, 512, 256, 0LL, 0LL, 0LL, 2, 0, 0, 0, 0, 0, 0);
    pack_wct_k<<<dim3(262144 / 256), blk, 0, stream>>>(t_ctw, Wct);
    // write transposed (B,D,64,32) from pathway's (32,64), + fout residual
    gemm_k<<<dim3(1, 256, 1), blk, 0, stream>>>(z, Wct, tout, t_ctb, fout,
        16384, 64, 4096, 0LL, 0LL, 0LL, 2, 2, 64, LT, 2, 2048, 64);

    // ---- attention ----
    gemm_k<<<dim3(3, 256, 1), blk, 0, stream>>>(tout, qkv_w, qkvb, qkv_b, nullptr,
        16384, 192, 64, 0LL, 0LL, 0LL, 2, 1, 2048, 0, 0, 0, 0);
    attn_k<<<dim3(32, NHEADS, BB), blk, 0, stream>>>(qkvb, attn);
    gemm_k<<<dim3(1, 256, 1), blk, 0, stream>>>(attn, ow, dp, ob, tout,
        16384, 64, 64, 0LL, 0LL, 0LL, 2, 0, 0, 0, 1, 2048, 0);

    // ---- reconstruction ----
    up_k<<<dim3(4194304 / 256), blk, 0, stream>>>(dp, upw0, upb0, x1, y1, T4, F4);
    up_k<<<dim3(16777216 / 256), blk, 0, stream>>>(y1, upw1, upb1, x0, y0, T2, F2);

    // final 1x1 conv: out[c][p] = fw[c][d] * y0[d][p] + fb[c]
    gemm_k<<<dim3(512, 4, 8), blk, 0, stream>>>(fw, y0, out, fb, nullptr,
        256, 32768, 64, 0LL, 2097152LL, 8388608LL, 1, 0, 0, 0, 0, 0, 0);
}

// Round 2
// 2766.063 us; speedup vs baseline: 1.4983x; 1.4983x over previous
//
#include <hip/hip_runtime.h>

// ---------------- problem constants ----------------
#define BB 8
#define CC 256
#define TT 256
#define FF 128
#define DD 64
#define HH 128
#define NHEADS 4
#define KK 8
#define II 512            // D*K
#define P1 32768          // T*F
#define T2 128
#define F2 64
#define P2 8192
#define T4 64
#define F4 32
#define P4 2048           // T4*F4

// freq pathway: N=512 seqs, L=25 ; time pathway: N=256 seqs, L=57
#define LF 25
#define LT 57
#define MF (512*LF)       // 12800
#define MT (256*LT)       // 14592

// ---------------- generic f32 tiled GEMM ----------------
// C[row][n] = sum_k A'[row][k] * B[k][n]  (+bias)(+resid), 64x64 tile, BK=32.
// a_mode: 0 A row-major [row*Kd+k] (+bb*sA)
//         1 A = src[(b2*Kd + k)*2048 + r], b2=row>>11, r=row&2047 (batched transpose, aR==2048)
//         2 convT gather: f=row%aR, tap=k>>9, i=k&511, l=f+tap-7; A=z[((row/aR)*convL+l)*512+i] or 0
// c_mode: 0 ci = bb*sC + row*N + n
//         1 ci = (b2*N + n)*cR + r           (channel-major per batch)
//         2 ci = (b2*N + n)*cR + ff*(cR/cF) + tt   (channel-major, spatial transpose)
__global__ __launch_bounds__(256) void gemm_k(
    const float* __restrict__ A, const float* __restrict__ Bm, float* __restrict__ Cm,
    const float* __restrict__ bias, const float* __restrict__ resid,
    int M, int N, int Kd,
    long long sA, long long sB, long long sC,
    int bias_mode, int a_mode, int aR, int convL,
    int c_mode, int cR, int cF)
{
    __shared__ float As[32][66];
    __shared__ float Bs[32][64];
    int bb = blockIdx.z;
    int m0 = blockIdx.y * 64, n0 = blockIdx.x * 64;
    int tid = threadIdx.x;
    int tn = tid & 15, tm = tid >> 4;

    float acc[4][4];
#pragma unroll
    for (int i = 0; i < 4; ++i)
#pragma unroll
        for (int j = 0; j < 4; ++j) acc[i][j] = 0.f;

    const float* Ab = A + (long long)bb * sA;
    const float* Bb = Bm + (long long)bb * sB;

    // precompute per-thread A staging bases
    long long abase[8]; int fo[8];
    if (a_mode == 1) {
        int mm = tid & 63; int row = m0 + mm;
        int b2 = row >> 11; int r = row & 2047;
        abase[0] = ((long long)b2 * Kd) * 2048 + r;
    } else if (a_mode == 0) {
#pragma unroll
        for (int j = 0; j < 8; ++j) {
            int mm = (tid >> 5) + 8 * j;
            abase[j] = (long long)(m0 + mm) * Kd;
        }
    } else {
#pragma unroll
        for (int j = 0; j < 8; ++j) {
            int mm = (tid >> 5) + 8 * j;
            int row = m0 + mm;
            fo[j] = row % aR;
            abase[j] = (long long)(row / aR) * convL;
        }
    }
    int nn_b = tid & 63;

    for (int k0 = 0; k0 < Kd; k0 += 32) {
        // stage A
        if (a_mode == 1) {
            int mm = tid & 63;
#pragma unroll
            for (int j = 0; j < 8; ++j) {
                int kk = (tid >> 6) + 4 * j;
                As[kk][mm] = A[abase[0] + (long long)(k0 + kk) * 2048];
            }
        } else if (a_mode == 0) {
            int kk = tid & 31;
#pragma unroll
            for (int j = 0; j < 8; ++j) {
                int mm = (tid >> 5) + 8 * j;
                As[kk][mm] = Ab[abase[j] + k0 + kk];
            }
        } else {
            int kk = tid & 31;
            int kg = k0 + kk;
            int tap = kg >> 9, ii = kg & 511;
#pragma unroll
            for (int j = 0; j < 8; ++j) {
                int mm = (tid >> 5) + 8 * j;
                int l = fo[j] + tap - 7;
                As[kk][mm] = (l >= 0 && l < convL) ? A[(abase[j] + l) * 512 + ii] : 0.f;
            }
        }
        // stage B
#pragma unroll
        for (int j = 0; j < 8; ++j) {
            int kk = (tid >> 6) + 4 * j;
            Bs[kk][nn_b] = Bb[(long long)(k0 + kk) * N + (n0 + nn_b)];
        }
        __syncthreads();
#pragma unroll
        for (int kk = 0; kk < 32; ++kk) {
            float av[4], bv[4];
#pragma unroll
            for (int x = 0; x < 4; ++x) av[x] = As[kk][tm * 4 + x];
#pragma unroll
            for (int y = 0; y < 4; ++y) bv[y] = Bs[kk][tn * 4 + y];
#pragma unroll
            for (int x = 0; x < 4; ++x)
#pragma unroll
                for (int y = 0; y < 4; ++y) acc[x][y] += av[x] * bv[y];
        }
        __syncthreads();
    }

#pragma unroll
    for (int x = 0; x < 4; ++x) {
        int row = m0 + tm * 4 + x;
#pragma unroll
        for (int y = 0; y < 4; ++y) {
            int n = n0 + tn * 4 + y;
            float v = acc[x][y];
            if (bias_mode == 1) v += bias[row];
            else if (bias_mode == 2) v += bias[n];
            long long ci;
            if (c_mode == 0) ci = (long long)bb * sC + (long long)row * N + n;
            else if (c_mode == 1) {
                int b2 = row / cR, r = row - b2 * cR;
                ci = ((long long)b2 * N + n) * cR + r;
            } else {
                int b2 = row / cR, r = row - b2 * cR;
                int tt = r / cF, ff = r - tt * cF;
                ci = ((long long)b2 * N + n) * cR + (long long)ff * (cR / cF) + tt;
            }
            if (resid) v += resid[ci];
            Cm[ci] = v;
        }
    }
}

// ---------------- 3x3 stride2 pad1 conv + ReLU, LDS-tiled implicit GEMM ----------------
// block = one (batch, 8x8 output tile), all 64 output channels.
// Per input channel: stage 17x17 input halo + 64x9 weights in LDS;
// each thread accumulates 4 channels x 4 pixels in registers.
__global__ __launch_bounds__(256) void down_tile_k(const float* __restrict__ in,
    const float* __restrict__ w, const float* __restrict__ bias,
    float* __restrict__ out, int Hi, int Wi)
{
    int Ho = Hi >> 1, Wo = Wi >> 1;
    int ntx = Wo >> 3, nty = Ho >> 3;
    int tx = blockIdx.x % ntx; int rest = blockIdx.x / ntx;
    int ty = rest % nty; int b = rest / nty;
    int y0 = ty * 8, x0 = tx * 8;
    __shared__ float Ws[64][9];
    __shared__ float Is[17][21];
    int tid = threadIdx.x;
    int tm = tid >> 4, tn = tid & 15;
    float acc[4][4];
#pragma unroll
    for (int i = 0; i < 4; ++i)
#pragma unroll
        for (int j = 0; j < 4; ++j) acc[i][j] = 0.f;

    const float* ib = in + (long long)b * 64 * Hi * Wi;
    for (int c = 0; c < 64; ++c) {
        // stage weights for this input channel: Ws[d][tap] = w[d][c][tap]
        for (int idx = tid; idx < 576; idx += 256) {
            int d = idx / 9, t = idx - d * 9;
            Ws[d][t] = w[((d << 6) + c) * 9 + t];
        }
        // stage 17x17 input patch (zero-padded at borders)
        const float* icp = ib + (long long)c * Hi * Wi;
        for (int idx = tid; idx < 289; idx += 256) {
            int r = idx / 17, s = idx - r * 17;
            int iy = 2 * y0 - 1 + r, ix = 2 * x0 - 1 + s;
            float v = 0.f;
            if (iy >= 0 && iy < Hi && ix >= 0 && ix < Wi) v = icp[(long long)iy * Wi + ix];
            Is[r][s] = v;
        }
        __syncthreads();
        float wr[4][9];
#pragma unroll
        for (int dd = 0; dd < 4; ++dd)
#pragma unroll
            for (int t = 0; t < 9; ++t) wr[dd][t] = Ws[tm * 4 + dd][t];
#pragma unroll
        for (int pp = 0; pp < 4; ++pp) {
            int p = tn * 4 + pp; int py = p >> 3, px = p & 7;
            float iv[9];
#pragma unroll
            for (int kh = 0; kh < 3; ++kh)
#pragma unroll
                for (int kw = 0; kw < 3; ++kw)
                    iv[kh * 3 + kw] = Is[2 * py + kh][2 * px + kw];
#pragma unroll
            for (int dd = 0; dd < 4; ++dd)
#pragma unroll
                for (int t = 0; t < 9; ++t) acc[dd][pp] += wr[dd][t] * iv[t];
        }
        __syncthreads();
    }
#pragma unroll
    for (int dd = 0; dd < 4; ++dd) {
        int d = tm * 4 + dd;
        float bsv = bias[d];
#pragma unroll
        for (int pp = 0; pp < 4; ++pp) {
            int p = tn * 4 + pp; int py = p >> 3, px = p & 7;
            out[(((long long)b * 64 + d) * Ho + (y0 + py)) * Wo + (x0 + px)] =
                fmaxf(acc[dd][pp] + bsv, 0.f);
        }
    }
}

// ---------------- unfolds (build u = im2col of ag along scan axis) ----------------
__global__ void unfold_freq_k(const float* __restrict__ ag, float* __restrict__ u)
{
    long long gid = (long long)blockIdx.x * blockDim.x + threadIdx.x;
    if (gid >= (long long)MF * II) return;
    int ch = (int)(gid & 511); int row = (int)(gid >> 9);
    int b = row / (T4 * LF); int rem = row - b * (T4 * LF);
    int t = rem / LF; int l = rem - t * LF;
    int d = ch >> 3, i = ch & 7;
    u[gid] = ag[((long long)((b * DD + d) * T4 + t)) * F4 + l + i];
}
__global__ void unfold_time_k(const float* __restrict__ ag, float* __restrict__ u)
{
    long long gid = (long long)blockIdx.x * blockDim.x + threadIdx.x;
    if (gid >= (long long)MT * II) return;
    int ch = (int)(gid & 511); int row = (int)(gid >> 9);
    int b = row / (F4 * LT); int rem = row - b * (F4 * LT);
    int tt = rem / LT; int l = rem - tt * LT;
    int d = ch >> 3, i = ch & 7;
    u[gid] = ag[((long long)((b * DD + d) * T4 + (l + i))) * F4 + tt];
}

// ---------------- weight packing ----------------
// Wcat[k][0:384]=Wx[0], [384:512]=Whw[0], [512:896]=Wx[1], [896:1024]=Whw[1]
__global__ void pack_wcat_k(const float* __restrict__ Wx, const float* __restrict__ Whw,
                            float* __restrict__ Wcat)
{
    int gid = blockIdx.x * blockDim.x + threadIdx.x;
    if (gid >= 512 * 1024) return;
    int col = gid & 1023; int k = gid >> 10;
    int dir = col >> 9; int c = col & 511;
    float v;
    if (c < 384) v = Wx[(dir * 512 + k) * 384 + c];
    else         v = Whw[(dir * 512 + k) * 128 + (c - 384)];
    Wcat[gid] = v;
}
// Wct[tap*512+i][d] = ctw[d][i][0][tap]
__global__ void pack_wct_k(const float* __restrict__ ctw, float* __restrict__ Wct)
{
    int gid = blockIdx.x * blockDim.x + threadIdx.x;
    if (gid >= 4096 * 64) return;
    int d = gid & 63; int kk = gid >> 6;
    int tap = kk >> 9, i = kk & 511;
    Wct[gid] = ctw[((d * 512) + i) * 8 + tap];
}

// ---------------- SRU elementwise recurrence ----------------
// G rows: [xt(0:128) fp(128:256) rp(256:384) xhw(384:512) | dir1: +512]
__global__ void sru_scan_k(const float* __restrict__ G, const float* __restrict__ bfw,
                           const float* __restrict__ brw, float* __restrict__ hout,
                           int Nn, int L)
{
    int gid = blockIdx.x * blockDim.x + threadIdx.x;
    if (gid >= Nn * 256) return;
    int h = gid & 127; int dir = (gid >> 7) & 1; int n = gid >> 8;
    const float bf = bfw[dir * 128 + h], br = brw[dir * 128 + h];
    int base = dir * 512 + h;
    float c = 0.f;
    for (int s = 0; s < L; ++s) {
        int l = dir ? (L - 1 - s) : s;
        const float* g = G + ((long long)(n * L + l)) * 1024 + base;
        float xt = g[0];
        float fv = 1.f / (1.f + __expf(-(g[128] + bf)));
        float rv = 1.f / (1.f + __expf(-(g[256] + br)));
        float xh = g[384];
        c = fv * c + (1.f - fv) * xt;
        float hv = rv * c + (1.f - rv) * xh;
        hout[((long long)(n * L + l)) * 256 + dir * 128 + h] = hv;
    }
}

// ---------------- flash attention (dh=16, 4 heads) ----------------
__global__ __launch_bounds__(256) void attn_k(const float* __restrict__ qkv, float* __restrict__ out)
{
    int mtile = blockIdx.x, head = blockIdx.y, b = blockIdx.z;
    int tid = threadIdx.x;
    int qi = tid & 63, quad = tid >> 6;
    int m = mtile * 64 + qi;
    const float* qrow = qkv + ((long long)(b * P4 + m)) * 192 + head * 16;
    float q[16];
#pragma unroll
    for (int d = 0; d < 16; ++d) q[d] = qrow[d] * 0.25f;  // 1/sqrt(16)
    __shared__ float Ks[64][16];
    __shared__ float Vs[64][16];
    __shared__ float red[64 * 4 * 18];
    float mmax = -1e30f, lsum = 0.f, acc[16];
#pragma unroll
    for (int d = 0; d < 16; ++d) acc[d] = 0.f;

    for (int j0 = 0; j0 < P4; j0 += 64) {
        __syncthreads();
        for (int e = tid; e < 1024; e += 256) {
            int key = e >> 4, dd = e & 15;
            long long basei = ((long long)(b * P4 + j0 + key)) * 192 + head * 16;
            Ks[key][dd] = qkv[basei + 64 + dd];
            Vs[key][dd] = qkv[basei + 128 + dd];
        }
        __syncthreads();
        for (int jj = quad; jj < 64; jj += 4) {
            float s = 0.f;
#pragma unroll
            for (int d = 0; d < 16; ++d) s += q[d] * Ks[jj][d];
            float nm = fmaxf(mmax, s);
            float corr = __expf(mmax - nm);
            float pj = __expf(s - nm);
            lsum = lsum * corr + pj;
#pragma unroll
            for (int d = 0; d < 16; ++d) acc[d] = acc[d] * corr + pj * Vs[jj][d];
            mmax = nm;
        }
    }
    __syncthreads();
    float* slot = red + (qi * 4 + quad) * 18;
    slot[0] = mmax; slot[1] = lsum;
#pragma unroll
    for (int d = 0; d < 16; ++d) slot[2 + d] = acc[d];
    __syncthreads();
    if (quad == 0) {
        float M = -1e30f;
        for (int t = 0; t < 4; ++t) M = fmaxf(M, red[(qi * 4 + t) * 18]);
        float L = 0.f; float o[16];
#pragma unroll
        for (int d = 0; d < 16; ++d) o[d] = 0.f;
        for (int t = 0; t < 4; ++t) {
            float* sl = red + (qi * 4 + t) * 18;
            float w = __expf(sl[0] - M);
            L += sl[1] * w;
#pragma unroll
            for (int d = 0; d < 16; ++d) o[d] += sl[2 + d] * w;
        }
        float inv = 1.f / L;
        float* op = out + ((long long)(b * P4 + m)) * 64 + head * 16;
#pragma unroll
        for (int d = 0; d < 16; ++d) op[d] = o[d] * inv;
    }
}

// ---------------- convT k=2 s=2 (exactly one tap per output) + residual ----------------
__global__ void up_k(const float* __restrict__ in, const float* __restrict__ w,
                     const float* __restrict__ bias, const float* __restrict__ resid,
                     float* __restrict__ out, int Hi, int Wi)
{
    int Ho = Hi * 2, Wo = Wi * 2;
    long long gid = (long long)blockIdx.x * blockDim.x + threadIdx.x;
    long long total = (long long)BB * DD * Ho * Wo;
    if (gid >= total) return;
    int x = (int)(gid % Wo); long long t1 = gid / Wo;
    int y = (int)(t1 % Ho); long long t2 = t1 / Ho;
    int d = (int)(t2 & 63); int b = (int)(t2 >> 6);
    int kh = 1 - (y & 1), kw = 1 - (x & 1);   // JAX conv_transpose: no kernel flip
    int iy = y >> 1, ix = x >> 1;
    float acc = bias[d];
    const float* ip = in + (long long)b * DD * Hi * Wi + (long long)iy * Wi + ix;
    const float* wp = w + d * DD * 4 + kh * 2 + kw;
    for (int c = 0; c < DD; ++c) acc += ip[(long long)c * Hi * Wi] * wp[c * 4];
    out[gid] = acc + resid[gid];
}

// ---------------- host launch ----------------
extern "C" void kernel_launch(void* const* d_in, const int* in_sizes, int n_in,
                              void* d_out, int out_size, void* d_ws, size_t ws_size,
                              hipStream_t stream)
{
    const float* A_in  = (const float*)d_in[0];
    const float* cw    = (const float*)d_in[1];
    const float* cb    = (const float*)d_in[2];
    const float* dw0   = (const float*)d_in[3];
    const float* db0   = (const float*)d_in[4];
    const float* dw1   = (const float*)d_in[5];
    const float* db1   = (const float*)d_in[6];
    const float* f_Wx  = (const float*)d_in[7];
    const float* f_bf  = (const float*)d_in[8];
    const float* f_br  = (const float*)d_in[9];
    const float* f_Whw = (const float*)d_in[10];
    const float* f_pw  = (const float*)d_in[11];
    const float* f_pb  = (const float*)d_in[12];
    const float* f_ctw = (const float*)d_in[13];
    const float* f_ctb = (const float*)d_in[14];
    const float* t_Wx  = (const float*)d_in[15];
    const float* t_bf  = (const float*)d_in[16];
    const float* t_br  = (const float*)d_in[17];
    const float* t_Whw = (const float*)d_in[18];
    const float* t_pw  = (const float*)d_in[19];
    const float* t_pb  = (const float*)d_in[20];
    const float* t_ctw = (const float*)d_in[21];
    const float* t_ctb = (const float*)d_in[22];
    const float* qkv_w = (const float*)d_in[23];
    const float* qkv_b = (const float*)d_in[24];
    const float* ow    = (const float*)d_in[25];
    const float* ob    = (const float*)d_in[26];
    const float* upw0  = (const float*)d_in[27];
    const float* upb0  = (const float*)d_in[28];
    const float* upw1  = (const float*)d_in[29];
    const float* upb1  = (const float*)d_in[30];
    const float* fw    = (const float*)d_in[31];
    const float* fb    = (const float*)d_in[32];

    float* ws  = (float*)d_ws;
    float* out = (float*)d_out;

    // workspace layout (floats)
    float* ag   = ws + 0;          // 1,048,576
    float* x1   = ws + 1048576;    // 4,194,304
    float* u    = ws + 5242880;    // 7,471,104 (later reused as y1)
    float* G    = ws + 12713984;   // 14,942,208 (later reused as y0, spills into h)
    float* hbuf = ws + 27656192;   // 3,735,552
    float* z    = ws + 31391744;   // 7,471,104
    float* Wcat = ws + 38862848;   // 524,288
    float* Wct  = ws + 39387136;   // 262,144
    float* fout = ws + 39649280;   // 1,048,576
    float* tout = ws + 40697856;   // 1,048,576
    float* qkvb = ws + 41746432;   // 3,145,728
    float* attn = ws + 44892160;   // 1,048,576
    float* dp   = ws + 45940736;   // 1,048,576  (total 46,989,312 floats ≈ 180 MiB)
    float* y1 = u;
    float* y0 = G;
    float* x0 = out;               // x0 parked in d_out (final conv reads only y0)

    dim3 blk(256);

    // 1. compress: per-b GEMM  x0[d][p] = cw[d][c] * A[c][p] + cb[d]
    gemm_k<<<dim3(512, 1, 8), blk, 0, stream>>>(cw, A_in, x0, cb, nullptr,
        64, 32768, 256, 0LL, 8388608LL, 2097152LL, 1, 0, 0, 0, 0, 0, 0);

    // 2-3. downsample (LDS-tiled implicit GEMM)
    down_tile_k<<<dim3(1024), blk, 0, stream>>>(x0, dw0, db0, x1, TT, FF);
    down_tile_k<<<dim3(256), blk, 0, stream>>>(x1, dw1, db1, ag, T2, F2);

    // ---- frequency pathway ----
    unfold_freq_k<<<dim3((MF * II) / 256), blk, 0, stream>>>(ag, u);
    pack_wcat_k<<<dim3(524288 / 256), blk, 0, stream>>>(f_Wx, f_Whw, Wcat);
    gemm_k<<<dim3(16, MF / 64, 1), blk, 0, stream>>>(u, Wcat, G, nullptr, nullptr,
        MF, 1024, 512, 0LL, 0LL, 0LL, 0, 0, 0, 0, 0, 0, 0);
    sru_scan_k<<<dim3(131072 / 256), blk, 0, stream>>>(G, f_bf, f_br, hbuf, 512, LF);
    gemm_k<<<dim3(8, MF / 64, 1), blk, 0, stream>>>(hbuf, f_pw, z, f_pb, nullptr,
        MF, 512, 256, 0LL, 0LL, 0LL, 2, 0, 0, 0, 0, 0, 0);
    pack_wct_k<<<dim3(262144 / 256), blk, 0, stream>>>(f_ctw, Wct);
    // convT(1,8) as GEMM K=4096; write (B,D,64,32), + ag residual, + ctb
    gemm_k<<<dim3(1, 256, 1), blk, 0, stream>>>(z, Wct, fout, f_ctb, ag,
        16384, 64, 4096, 0LL, 0LL, 0LL, 2, 2, 32, LF, 1, 2048, 0);

    // ---- time pathway ----
    unfold_time_k<<<dim3((MT * II) / 256), blk, 0, stream>>>(ag, u);
    pack_wcat_k<<<dim3(524288 / 256), blk, 0, stream>>>(t_Wx, t_Whw, Wcat);
    gemm_k<<<dim3(16, MT / 64, 1), blk, 0, stream>>>(u, Wcat, G, nullptr, nullptr,
        MT, 1024, 512, 0LL, 0LL, 0LL, 0, 0, 0, 0, 0, 0, 0);
    sru_scan_k<<<dim3(65536 / 256), blk, 0, stream>>>(G, t_bf, t_br, hbuf, 256, LT);
    gemm_k<<<dim3(8, MT / 64, 1), blk, 0, stream>>>(hbuf, t_pw, z, t_pb, nullptr,
        MT, 512, 256, 0LL, 0LL, 0LL, 2, 0, 0, 0, 0, 0, 0);
    pack_wct_k<<<dim3(262144 / 256), blk, 0, stream>>>(t_ctw, Wct);
    // write transposed (B,D,64,32) from pathway's (32,64), + fout residual
    gemm_k<<<dim3(1, 256, 1), blk, 0, stream>>>(z, Wct, tout, t_ctb, fout,
        16384, 64, 4096, 0LL, 0LL, 0LL, 2, 2, 64, LT, 2, 2048, 64);

    // ---- attention ----
    gemm_k<<<dim3(3, 256, 1), blk, 0, stream>>>(tout, qkv_w, qkvb, qkv_b, nullptr,
        16384, 192, 64, 0LL, 0LL, 0LL, 2, 1, 2048, 0, 0, 0, 0);
    attn_k<<<dim3(32, NHEADS, BB), blk, 0, stream>>>(qkvb, attn);
    gemm_k<<<dim3(1, 256, 1), blk, 0, stream>>>(attn, ow, dp, ob, tout,
        16384, 64, 64, 0LL, 0LL, 0LL, 2, 0, 0, 0, 1, 2048, 0);

    // ---- reconstruction ----
    up_k<<<dim3(4194304 / 256), blk, 0, stream>>>(dp, upw0, upb0, x1, y1, T4, F4);
    up_k<<<dim3(16777216 / 256), blk, 0, stream>>>(y1, upw1, upb1, x0, y0, T2, F2);

    // final 1x1 conv: out[c][p] = fw[c][d] * y0[d][p] + fb[c]
    gemm_k<<<dim3(512, 4, 8), blk, 0, stream>>>(fw, y0, out, fb, nullptr,
        256, 32768, 64, 0LL, 2097152LL, 8388608LL, 1, 0, 0, 0, 0, 0, 0);
}

// Round 3
// 1522.596 us; speedup vs baseline: 2.7219x; 1.8167x over previous
//
#include <hip/hip_runtime.h>

// ---------------- problem constants ----------------
#define BB 8
#define CC 256
#define TT 256
#define FF 128
#define DD 64
#define HH 128
#define NHEADS 4
#define KK 8
#define II 512            // D*K
#define T2 128
#define F2 64
#define T4 64
#define F4 32
#define P4 2048           // T4*F4

// freq pathway: N=512 seqs, L=25 ; time pathway: N=256 seqs, L=57
#define LF 25
#define LT 57
#define MF (512*LF)       // 12800
#define MT (256*LT)       // 14592

typedef __attribute__((ext_vector_type(8))) short bf16x8;
typedef __attribute__((ext_vector_type(4))) float f32x4;

__device__ __forceinline__ ushort f2b(float x) {
    unsigned u = __float_as_uint(x);
    unsigned r = (u + 0x7FFFu + ((u >> 16) & 1u)) >> 16;
    return (ushort)r;
}

// ---------------- generic f32 tiled GEMM (compress / qkv / attn-out / final) ----------------
// a_mode: 0 row-major; 1 batched transpose (src[(b2*Kd+k)*2048 + r])
// c_mode: 0 row-major (+bb*sC); 1 channel-major per batch
__global__ __launch_bounds__(256) void gemm_k(
    const float* __restrict__ A, const float* __restrict__ Bm, float* __restrict__ Cm,
    const float* __restrict__ bias, const float* __restrict__ resid,
    int M, int N, int Kd,
    long long sA, long long sB, long long sC,
    int bias_mode, int a_mode, int c_mode, int cR)
{
    __shared__ float As[32][66];
    __shared__ float Bs[32][64];
    int bb = blockIdx.z;
    int m0 = blockIdx.y * 64, n0 = blockIdx.x * 64;
    int tid = threadIdx.x;
    int tn = tid & 15, tm = tid >> 4;

    float acc[4][4];
#pragma unroll
    for (int i = 0; i < 4; ++i)
#pragma unroll
        for (int j = 0; j < 4; ++j) acc[i][j] = 0.f;

    const float* Ab = A + (long long)bb * sA;
    const float* Bb = Bm + (long long)bb * sB;

    long long abase[8];
    if (a_mode == 1) {
        int mm = tid & 63; int row = m0 + mm;
        int b2 = row >> 11; int r = row & 2047;
        abase[0] = ((long long)b2 * Kd) * 2048 + r;
    } else {
#pragma unroll
        for (int j = 0; j < 8; ++j) {
            int mm = (tid >> 5) + 8 * j;
            abase[j] = (long long)(m0 + mm) * Kd;
        }
    }
    int nn_b = tid & 63;

    for (int k0 = 0; k0 < Kd; k0 += 32) {
        if (a_mode == 1) {
            int mm = tid & 63;
#pragma unroll
            for (int j = 0; j < 8; ++j) {
                int kk = (tid >> 6) + 4 * j;
                As[kk][mm] = A[abase[0] + (long long)(k0 + kk) * 2048];
            }
        } else {
            int kk = tid & 31;
#pragma unroll
            for (int j = 0; j < 8; ++j) {
                int mm = (tid >> 5) + 8 * j;
                As[kk][mm] = Ab[abase[j] + k0 + kk];
            }
        }
#pragma unroll
        for (int j = 0; j < 8; ++j) {
            int kk = (tid >> 6) + 4 * j;
            Bs[kk][nn_b] = Bb[(long long)(k0 + kk) * N + (n0 + nn_b)];
        }
        __syncthreads();
#pragma unroll
        for (int kk = 0; kk < 32; ++kk) {
            float av[4], bv[4];
#pragma unroll
            for (int x = 0; x < 4; ++x) av[x] = As[kk][tm * 4 + x];
#pragma unroll
            for (int y = 0; y < 4; ++y) bv[y] = Bs[kk][tn * 4 + y];
#pragma unroll
            for (int x = 0; x < 4; ++x)
#pragma unroll
                for (int y = 0; y < 4; ++y) acc[x][y] += av[x] * bv[y];
        }
        __syncthreads();
    }

#pragma unroll
    for (int x = 0; x < 4; ++x) {
        int row = m0 + tm * 4 + x;
#pragma unroll
        for (int y = 0; y < 4; ++y) {
            int n = n0 + tn * 4 + y;
            float v = acc[x][y];
            if (bias_mode == 1) v += bias[row];
            else if (bias_mode == 2) v += bias[n];
            long long ci;
            if (c_mode == 0) ci = (long long)bb * sC + (long long)row * N + n;
            else {
                int b2 = row / cR, r = row - b2 * cR;
                ci = ((long long)b2 * N + n) * cR + r;
            }
            if (resid) v += resid[ci];
            Cm[ci] = v;
        }
    }
}

// ---------------- bf16 MFMA GEMM: C(MxN) = A16(MxK) * BT16(NxK)^T ----------------
// 128x128 block tile, 4 waves (2x2 of 64x64), 16x16x32 fragments.
__global__ __launch_bounds__(256) void mfma_gemm_k(
    const ushort* __restrict__ A16, const ushort* __restrict__ BT16,
    float* __restrict__ C, ushort* __restrict__ C16,
    const float* __restrict__ bias,
    int M, int N, int K, int out16)
{
    __shared__ ushort As[128][40];
    __shared__ ushort Bs[128][40];
    int m0 = blockIdx.y * 128, n0 = blockIdx.x * 128;
    int tid = threadIdx.x;
    int wave = tid >> 6, lane = tid & 63;
    int wm = (wave & 1) * 64, wn = (wave >> 1) * 64;
    int l15 = lane & 15, lhi = lane >> 4;
    f32x4 acc[4][4] = {};
    int rs = tid >> 2, qs = tid & 3;

    for (int k0 = 0; k0 < K; k0 += 32) {
        *(uint4*)&As[rs][qs * 8]      = *(const uint4*)(A16 + (long long)(m0 + rs) * K + k0 + qs * 8);
        *(uint4*)&As[rs + 64][qs * 8] = *(const uint4*)(A16 + (long long)(m0 + rs + 64) * K + k0 + qs * 8);
        *(uint4*)&Bs[rs][qs * 8]      = *(const uint4*)(BT16 + (long long)(n0 + rs) * K + k0 + qs * 8);
        *(uint4*)&Bs[rs + 64][qs * 8] = *(const uint4*)(BT16 + (long long)(n0 + rs + 64) * K + k0 + qs * 8);
        __syncthreads();
        bf16x8 af[4], bfr[4];
#pragma unroll
        for (int fr = 0; fr < 4; ++fr)
            af[fr] = *(const bf16x8*)&As[wm + fr * 16 + l15][lhi * 8];
#pragma unroll
        for (int fc = 0; fc < 4; ++fc)
            bfr[fc] = *(const bf16x8*)&Bs[wn + fc * 16 + l15][lhi * 8];
#pragma unroll
        for (int fr = 0; fr < 4; ++fr)
#pragma unroll
            for (int fc = 0; fc < 4; ++fc)
                acc[fr][fc] = __builtin_amdgcn_mfma_f32_16x16x32_bf16(af[fr], bfr[fc], acc[fr][fc], 0, 0, 0);
        __syncthreads();
    }
#pragma unroll
    for (int fr = 0; fr < 4; ++fr) {
#pragma unroll
        for (int fc = 0; fc < 4; ++fc) {
            int col = n0 + wn + fc * 16 + l15;
            float bv = bias ? bias[col] : 0.f;
#pragma unroll
            for (int r = 0; r < 4; ++r) {
                int row = m0 + wm + fr * 16 + lhi * 4 + r;
                float v = acc[fr][fc][r] + bv;
                long long ci = (long long)row * N + col;
                if (out16) C16[ci] = f2b(v);
                else       C[ci] = v;
            }
        }
    }
}

// ---------------- convT(1,8) tap-reduce ----------------
// out[(b,d,·,·)] = bias[d] + resid + sum_tap Y[((b*NS+s)*L + p+tap-7)*512 + tap*64+d]
// freq: NS=64(t), FO=32(f), swap=0 -> out[((b*64+d)*NS+s)*FO+p]
// time: NS=32(ff), FO=64(tt), swap=1 -> out[((b*64+d)*FO+p)*NS+s]
__global__ void convt_reduce_k(const float* __restrict__ Y, const float* __restrict__ bias,
                               const float* __restrict__ resid, float* __restrict__ out,
                               int NS, int L, int FO, int swap)
{
    int gid = blockIdx.x * blockDim.x + threadIdx.x;
    int total = BB * 64 * NS * FO;
    if (gid >= total) return;
    int d = gid & 63; int rest = gid >> 6;
    int p = rest % FO; rest /= FO;
    int s = rest % NS; int b = rest / NS;
    float v = bias[d];
    long long ybase = ((long long)(b * NS + s)) * L;
#pragma unroll
    for (int tap = 0; tap < 8; ++tap) {
        int l = p + tap - 7;
        if (l >= 0 && l < L) v += Y[(ybase + l) * 512 + tap * 64 + d];
    }
    long long oi = swap ? (((long long)(b * 64 + d) * FO + p) * NS + s)
                        : (((long long)(b * 64 + d) * NS + s) * FO + p);
    out[oi] = v + resid[oi];
}

// ---------------- 3x3 stride2 pad1 conv + ReLU, LDS-tiled ----------------
__global__ __launch_bounds__(256) void down_tile_k(const float* __restrict__ in,
    const float* __restrict__ w, const float* __restrict__ bias,
    float* __restrict__ out, int Hi, int Wi)
{
    int Ho = Hi >> 1, Wo = Wi >> 1;
    int ntx = Wo >> 3, nty = Ho >> 3;
    int tx = blockIdx.x % ntx; int rest = blockIdx.x / ntx;
    int ty = rest % nty; int b = rest / nty;
    int y0 = ty * 8, x0 = tx * 8;
    __shared__ float Ws[64][9];
    __shared__ float Is[17][21];
    int tid = threadIdx.x;
    int tm = tid >> 4, tn = tid & 15;
    float acc[4][4];
#pragma unroll
    for (int i = 0; i < 4; ++i)
#pragma unroll
        for (int j = 0; j < 4; ++j) acc[i][j] = 0.f;

    const float* ib = in + (long long)b * 64 * Hi * Wi;
    for (int c = 0; c < 64; ++c) {
        for (int idx = tid; idx < 576; idx += 256) {
            int d = idx / 9, t = idx - d * 9;
            Ws[d][t] = w[((d << 6) + c) * 9 + t];
        }
        const float* icp = ib + (long long)c * Hi * Wi;
        for (int idx = tid; idx < 289; idx += 256) {
            int r = idx / 17, s = idx - r * 17;
            int iy = 2 * y0 - 1 + r, ix = 2 * x0 - 1 + s;
            float v = 0.f;
            if (iy >= 0 && iy < Hi && ix >= 0 && ix < Wi) v = icp[(long long)iy * Wi + ix];
            Is[r][s] = v;
        }
        __syncthreads();
        float wr[4][9];
#pragma unroll
        for (int dd = 0; dd < 4; ++dd)
#pragma unroll
            for (int t = 0; t < 9; ++t) wr[dd][t] = Ws[tm * 4 + dd][t];
#pragma unroll
        for (int pp = 0; pp < 4; ++pp) {
            int p = tn * 4 + pp; int py = p >> 3, px = p & 7;
            float iv[9];
#pragma unroll
            for (int kh = 0; kh < 3; ++kh)
#pragma unroll
                for (int kw = 0; kw < 3; ++kw)
                    iv[kh * 3 + kw] = Is[2 * py + kh][2 * px + kw];
#pragma unroll
            for (int dd = 0; dd < 4; ++dd)
#pragma unroll
                for (int t = 0; t < 9; ++t) acc[dd][pp] += wr[dd][t] * iv[t];
        }
        __syncthreads();
    }
#pragma unroll
    for (int dd = 0; dd < 4; ++dd) {
        int d = tm * 4 + dd;
        float bsv = bias[d];
#pragma unroll
        for (int pp = 0; pp < 4; ++pp) {
            int p = tn * 4 + pp; int py = p >> 3, px = p & 7;
            out[(((long long)b * 64 + d) * Ho + (y0 + py)) * Wo + (x0 + px)] =
                fmaxf(acc[dd][pp] + bsv, 0.f);
        }
    }
}

// ---------------- unfolds -> bf16 ----------------
__global__ void unfold_freq_k(const float* __restrict__ ag, ushort* __restrict__ u)
{
    long long gid = (long long)blockIdx.x * blockDim.x + threadIdx.x;
    if (gid >= (long long)MF * II) return;
    int ch = (int)(gid & 511); int row = (int)(gid >> 9);
    int b = row / (T4 * LF); int rem = row - b * (T4 * LF);
    int t = rem / LF; int l = rem - t * LF;
    int d = ch >> 3, i = ch & 7;
    u[gid] = f2b(ag[((long long)((b * DD + d) * T4 + t)) * F4 + l + i]);
}
__global__ void unfold_time_k(const float* __restrict__ ag, ushort* __restrict__ u)
{
    long long gid = (long long)blockIdx.x * blockDim.x + threadIdx.x;
    if (gid >= (long long)MT * II) return;
    int ch = (int)(gid & 511); int row = (int)(gid >> 9);
    int b = row / (F4 * LT); int rem = row - b * (F4 * LT);
    int tt = rem / LT; int l = rem - tt * LT;
    int d = ch >> 3, i = ch & 7;
    u[gid] = f2b(ag[((long long)((b * DD + d) * T4 + (l + i))) * F4 + tt]);
}

// ---------------- weight packing (transposed, bf16) ----------------
// WcatT[n(1024)][k(512)]: n = dir*512 + c; c<384 -> Wx[dir][k][c], else Whw[dir][k][c-384]
__global__ void pack_wcatT_k(const float* __restrict__ Wx, const float* __restrict__ Whw,
                             ushort* __restrict__ WT)
{
    int gid = blockIdx.x * blockDim.x + threadIdx.x;
    if (gid >= 1024 * 512) return;
    int k = gid & 511; int n = gid >> 9;
    int dir = n >> 9; int c = n & 511;
    float v = (c < 384) ? Wx[(dir * 512 + k) * 384 + c]
                        : Whw[(dir * 512 + k) * 128 + (c - 384)];
    WT[gid] = f2b(v);
}
// pwT[n(512)][k(256)] = pw[k][n]
__global__ void pack_pwT_k(const float* __restrict__ pw, ushort* __restrict__ WT)
{
    int gid = blockIdx.x * blockDim.x + threadIdx.x;
    if (gid >= 512 * 256) return;
    int k = gid & 255; int n = gid >> 8;
    WT[gid] = f2b(pw[k * 512 + n]);
}
// Wct2T[n(512)][k(512)]: n = tap*64+d, k = i; val = ctw[d][i][tap]
__global__ void pack_wct2T_k(const float* __restrict__ ctw, ushort* __restrict__ WT)
{
    int gid = blockIdx.x * blockDim.x + threadIdx.x;
    if (gid >= 512 * 512) return;
    int k = gid & 511; int n = gid >> 9;
    int tap = n >> 6, d = n & 63;
    WT[gid] = f2b(ctw[((d * 512) + k) * 8 + tap]);
}

// ---------------- SRU elementwise recurrence (G f32 -> h bf16) ----------------
__global__ void sru_scan_k(const float* __restrict__ G, const float* __restrict__ bfw,
                           const float* __restrict__ brw, ushort* __restrict__ hout,
                           int Nn, int L)
{
    int gid = blockIdx.x * blockDim.x + threadIdx.x;
    if (gid >= Nn * 256) return;
    int h = gid & 127; int dir = (gid >> 7) & 1; int n = gid >> 8;
    const float bf = bfw[dir * 128 + h], br = brw[dir * 128 + h];
    int base = dir * 512 + h;
    float c = 0.f;
    for (int s = 0; s < L; ++s) {
        int l = dir ? (L - 1 - s) : s;
        const float* g = G + ((long long)(n * L + l)) * 1024 + base;
        float xt = g[0];
        float fv = 1.f / (1.f + __expf(-(g[128] + bf)));
        float rv = 1.f / (1.f + __expf(-(g[256] + br)));
        float xh = g[384];
        c = fv * c + (1.f - fv) * xt;
        float hv = rv * c + (1.f - rv) * xh;
        hout[((long long)(n * L + l)) * 256 + dir * 128 + h] = f2b(hv);
    }
}

// ---------------- flash attention (dh=16, 4 heads) ----------------
__global__ __launch_bounds__(256) void attn_k(const float* __restrict__ qkv, float* __restrict__ out)
{
    int mtile = blockIdx.x, head = blockIdx.y, b = blockIdx.z;
    int tid = threadIdx.x;
    int qi = tid & 63, quad = tid >> 6;
    int m = mtile * 64 + qi;
    const float* qrow = qkv + ((long long)(b * P4 + m)) * 192 + head * 16;
    float q[16];
#pragma unroll
    for (int d = 0; d < 16; ++d) q[d] = qrow[d] * 0.25f;
    __shared__ float Ks[64][16];
    __shared__ float Vs[64][16];
    __shared__ float red[64 * 4 * 18];
    float mmax = -1e30f, lsum = 0.f, acc[16];
#pragma unroll
    for (int d = 0; d < 16; ++d) acc[d] = 0.f;

    for (int j0 = 0; j0 < P4; j0 += 64) {
        __syncthreads();
        for (int e = tid; e < 1024; e += 256) {
            int key = e >> 4, dd = e & 15;
            long long basei = ((long long)(b * P4 + j0 + key)) * 192 + head * 16;
            Ks[key][dd] = qkv[basei + 64 + dd];
            Vs[key][dd] = qkv[basei + 128 + dd];
        }
        __syncthreads();
        for (int jj = quad; jj < 64; jj += 4) {
            float s = 0.f;
#pragma unroll
            for (int d = 0; d < 16; ++d) s += q[d] * Ks[jj][d];
            float nm = fmaxf(mmax, s);
            float corr = __expf(mmax - nm);
            float pj = __expf(s - nm);
            lsum = lsum * corr + pj;
#pragma unroll
            for (int d = 0; d < 16; ++d) acc[d] = acc[d] * corr + pj * Vs[jj][d];
            mmax = nm;
        }
    }
    __syncthreads();
    float* slot = red + (qi * 4 + quad) * 18;
    slot[0] = mmax; slot[1] = lsum;
#pragma unroll
    for (int d = 0; d < 16; ++d) slot[2 + d] = acc[d];
    __syncthreads();
    if (quad == 0) {
        float M = -1e30f;
        for (int t = 0; t < 4; ++t) M = fmaxf(M, red[(qi * 4 + t) * 18]);
        float L = 0.f; float o[16];
#pragma unroll
        for (int d = 0; d < 16; ++d) o[d] = 0.f;
        for (int t = 0; t < 4; ++t) {
            float* sl = red + (qi * 4 + t) * 18;
            float w = __expf(sl[0] - M);
            L += sl[1] * w;
#pragma unroll
            for (int d = 0; d < 16; ++d) o[d] += sl[2 + d] * w;
        }
        float inv = 1.f / L;
        float* op = out + ((long long)(b * P4 + m)) * 64 + head * 16;
#pragma unroll
        for (int d = 0; d < 16; ++d) op[d] = o[d] * inv;
    }
}

// ---------------- convT k=2 s=2 + residual ----------------
__global__ void up_k(const float* __restrict__ in, const float* __restrict__ w,
                     const float* __restrict__ bias, const float* __restrict__ resid,
                     float* __restrict__ out, int Hi, int Wi)
{
    int Ho = Hi * 2, Wo = Wi * 2;
    long long gid = (long long)blockIdx.x * blockDim.x + threadIdx.x;
    long long total = (long long)BB * DD * Ho * Wo;
    if (gid >= total) return;
    int x = (int)(gid % Wo); long long t1 = gid / Wo;
    int y = (int)(t1 % Ho); long long t2 = t1 / Ho;
    int d = (int)(t2 & 63); int b = (int)(t2 >> 6);
    int kh = 1 - (y & 1), kw = 1 - (x & 1);
    int iy = y >> 1, ix = x >> 1;
    float acc = bias[d];
    const float* ip = in + (long long)b * DD * Hi * Wi + (long long)iy * Wi + ix;
    const float* wp = w + d * DD * 4 + kh * 2 + kw;
    for (int c = 0; c < DD; ++c) acc += ip[(long long)c * Hi * Wi] * wp[c * 4];
    out[gid] = acc + resid[gid];
}

// ---------------- host launch ----------------
extern "C" void kernel_launch(void* const* d_in, const int* in_sizes, int n_in,
                              void* d_out, int out_size, void* d_ws, size_t ws_size,
                              hipStream_t stream)
{
    const float* A_in  = (const float*)d_in[0];
    const float* cw    = (const float*)d_in[1];
    const float* cb    = (const float*)d_in[2];
    const float* dw0   = (const float*)d_in[3];
    const float* db0   = (const float*)d_in[4];
    const float* dw1   = (const float*)d_in[5];
    const float* db1   = (const float*)d_in[6];
    const float* f_Wx  = (const float*)d_in[7];
    const float* f_bf  = (const float*)d_in[8];
    const float* f_br  = (const float*)d_in[9];
    const float* f_Whw = (const float*)d_in[10];
    const float* f_pw  = (const float*)d_in[11];
    const float* f_pb  = (const float*)d_in[12];
    const float* f_ctw = (const float*)d_in[13];
    const float* f_ctb = (const float*)d_in[14];
    const float* t_Wx  = (const float*)d_in[15];
    const float* t_bf  = (const float*)d_in[16];
    const float* t_br  = (const float*)d_in[17];
    const float* t_Whw = (const float*)d_in[18];
    const float* t_pw  = (const float*)d_in[19];
    const float* t_pb  = (const float*)d_in[20];
    const float* t_ctw = (const float*)d_in[21];
    const float* t_ctb = (const float*)d_in[22];
    const float* qkv_w = (const float*)d_in[23];
    const float* qkv_b = (const float*)d_in[24];
    const float* ow    = (const float*)d_in[25];
    const float* ob    = (const float*)d_in[26];
    const float* upw0  = (const float*)d_in[27];
    const float* upb0  = (const float*)d_in[28];
    const float* upw1  = (const float*)d_in[29];
    const float* upb1  = (const float*)d_in[30];
    const float* fw    = (const float*)d_in[31];
    const float* fb    = (const float*)d_in[32];

    float* ws  = (float*)d_ws;
    float* out = (float*)d_out;

    // workspace layout (f32 units)
    float* ag    = ws + 0;          // 1,048,576
    float* x1    = ws + 1048576;    // 4,194,304
    float* Ureg  = ws + 5242880;    // 7,471,104 : u16 (ushort) / Y (f32) / y1 (f32)
    float* G     = ws + 12713984;   // 14,942,208 (later y0, spills into h16 region)
    float* h16f  = ws + 27656192;   // 1,867,776 (h bf16)
    float* z16f  = ws + 29523968;   // 3,735,552 (z bf16)
    float* wcatf = ws + 33259520;   // 262,144 (WcatT bf16)
    float* wct2f = ws + 33521664;   // 131,072 (Wct2T bf16)
    float* pwtf  = ws + 33652736;   // 65,536 (pwT bf16)
    float* fout  = ws + 33718272;   // 1,048,576
    float* tout  = ws + 34766848;   // 1,048,576
    float* qkvb  = ws + 35815424;   // 3,145,728
    float* attnO = ws + 38961152;   // 1,048,576
    float* dp    = ws + 40009728;   // 1,048,576  (end 41,058,304 f32)
    ushort* u16    = (ushort*)Ureg;
    float*  Y      = Ureg;
    float*  y1     = Ureg;
    float*  y0     = G;
    ushort* h16    = (ushort*)h16f;
    ushort* z16    = (ushort*)z16f;
    ushort* WcatT  = (ushort*)wcatf;
    ushort* Wct2T  = (ushort*)wct2f;
    ushort* pwT    = (ushort*)pwtf;
    float*  x0     = out;           // x0 parked in d_out

    dim3 blk(256);

    // 1. compress: x0[d][p] = cw[d][c]*A[c][p] + cb[d]
    gemm_k<<<dim3(512, 1, 8), blk, 0, stream>>>(cw, A_in, x0, cb, nullptr,
        64, 32768, 256, 0LL, 8388608LL, 2097152LL, 1, 0, 0, 0);

    // 2-3. downsample
    down_tile_k<<<dim3(1024), blk, 0, stream>>>(x0, dw0, db0, x1, TT, FF);
    down_tile_k<<<dim3(256), blk, 0, stream>>>(x1, dw1, db1, ag, T2, F2);

    // ---- frequency pathway ----
    unfold_freq_k<<<dim3((MF * II) / 256), blk, 0, stream>>>(ag, u16);
    pack_wcatT_k<<<dim3(2048), blk, 0, stream>>>(f_Wx, f_Whw, WcatT);
    mfma_gemm_k<<<dim3(8, MF / 128), blk, 0, stream>>>(u16, WcatT, G, nullptr, nullptr,
        MF, 1024, 512, 0);
    sru_scan_k<<<dim3(131072 / 256), blk, 0, stream>>>(G, f_bf, f_br, h16, 512, LF);
    pack_pwT_k<<<dim3(512), blk, 0, stream>>>(f_pw, pwT);
    mfma_gemm_k<<<dim3(4, MF / 128), blk, 0, stream>>>(h16, pwT, nullptr, z16, f_pb,
        MF, 512, 256, 1);
    pack_wct2T_k<<<dim3(1024), blk, 0, stream>>>(f_ctw, Wct2T);
    mfma_gemm_k<<<dim3(4, MF / 128), blk, 0, stream>>>(z16, Wct2T, Y, nullptr, nullptr,
        MF, 512, 512, 0);
    convt_reduce_k<<<dim3(4096), blk, 0, stream>>>(Y, f_ctb, ag, fout, 64, LF, 32, 0);

    // ---- time pathway ----
    unfold_time_k<<<dim3((MT * II) / 256), blk, 0, stream>>>(ag, u16);
    pack_wcatT_k<<<dim3(2048), blk, 0, stream>>>(t_Wx, t_Whw, WcatT);
    mfma_gemm_k<<<dim3(8, MT / 128), blk, 0, stream>>>(u16, WcatT, G, nullptr, nullptr,
        MT, 1024, 512, 0);
    sru_scan_k<<<dim3(65536 / 256), blk, 0, stream>>>(G, t_bf, t_br, h16, 256, LT);
    pack_pwT_k<<<dim3(512), blk, 0, stream>>>(t_pw, pwT);
    mfma_gemm_k<<<dim3(4, MT / 128), blk, 0, stream>>>(h16, pwT, nullptr, z16, t_pb,
        MT, 512, 256, 1);
    pack_wct2T_k<<<dim3(1024), blk, 0, stream>>>(t_ctw, Wct2T);
    mfma_gemm_k<<<dim3(4, MT / 128), blk, 0, stream>>>(z16, Wct2T, Y, nullptr, nullptr,
        MT, 512, 512, 0);
    convt_reduce_k<<<dim3(4096), blk, 0, stream>>>(Y, t_ctb, fout, tout, 32, LT, 64, 1);

    // ---- attention ----
    gemm_k<<<dim3(3, 256, 1), blk, 0, stream>>>(tout, qkv_w, qkvb, qkv_b, nullptr,
        16384, 192, 64, 0LL, 0LL, 0LL, 2, 1, 0, 0);
    attn_k<<<dim3(32, NHEADS, BB), blk, 0, stream>>>(qkvb, attnO);
    gemm_k<<<dim3(1, 256, 1), blk, 0, stream>>>(attnO, ow, dp, ob, tout,
        16384, 64, 64, 0LL, 0LL, 0LL, 2, 0, 1, 2048);

    // ---- reconstruction ----
    up_k<<<dim3(4194304 / 256), blk, 0, stream>>>(dp, upw0, upb0, x1, y1, T4, F4);
    up_k<<<dim3(16777216 / 256), blk, 0, stream>>>(y1, upw1, upb1, x0, y0, T2, F2);

    // final 1x1 conv
    gemm_k<<<dim3(512, 4, 8), blk, 0, stream>>>(fw, y0, out, fb, nullptr,
        256, 32768, 64, 0LL, 2097152LL, 8388608LL, 1, 0, 0, 0);
}

// Round 4
// 1126.007 us; speedup vs baseline: 3.6806x; 1.3522x over previous
//
#include <hip/hip_runtime.h>

// ---------------- problem constants ----------------
#define BB 8
#define CC 256
#define TT 256
#define FF 128
#define DD 64
#define HH 128
#define NHEADS 4
#define KK 8
#define II 512            // D*K
#define T2 128
#define F2 64
#define T4 64
#define F4 32
#define P4 2048           // T4*F4

// freq pathway: N=512 seqs, L=25 ; time pathway: N=256 seqs, L=57
#define LF 25
#define LT 57
#define MF (512*LF)       // 12800
#define MT (256*LT)       // 14592

typedef __attribute__((ext_vector_type(8))) short bf16x8;
typedef __attribute__((ext_vector_type(4))) float f32x4;

__device__ __forceinline__ ushort f2b(float x) {
    unsigned u = __float_as_uint(x);
    unsigned r = (u + 0x7FFFu + ((u >> 16) & 1u)) >> 16;
    return (ushort)r;
}
__device__ __forceinline__ unsigned cvtpk_bf16(float lo, float hi) {
    unsigned r;
    asm("v_cvt_pk_bf16_f32 %0, %1, %2" : "=v"(r) : "v"(lo), "v"(hi));
    return r;
}

// ---------------- generic f32 tiled GEMM (qkv / attn-out) ----------------
__global__ __launch_bounds__(256) void gemm_k(
    const float* __restrict__ A, const float* __restrict__ Bm, float* __restrict__ Cm,
    const float* __restrict__ bias, const float* __restrict__ resid,
    int M, int N, int Kd,
    long long sA, long long sB, long long sC,
    int bias_mode, int a_mode, int c_mode, int cR)
{
    __shared__ float As[32][66];
    __shared__ float Bs[32][64];
    int bb = blockIdx.z;
    int m0 = blockIdx.y * 64, n0 = blockIdx.x * 64;
    int tid = threadIdx.x;
    int tn = tid & 15, tm = tid >> 4;

    float acc[4][4];
#pragma unroll
    for (int i = 0; i < 4; ++i)
#pragma unroll
        for (int j = 0; j < 4; ++j) acc[i][j] = 0.f;

    const float* Ab = A + (long long)bb * sA;
    const float* Bb = Bm + (long long)bb * sB;

    long long abase[8];
    if (a_mode == 1) {
        int mm = tid & 63; int row = m0 + mm;
        int b2 = row >> 11; int r = row & 2047;
        abase[0] = ((long long)b2 * Kd) * 2048 + r;
    } else {
#pragma unroll
        for (int j = 0; j < 8; ++j) {
            int mm = (tid >> 5) + 8 * j;
            abase[j] = (long long)(m0 + mm) * Kd;
        }
    }
    int nn_b = tid & 63;

    for (int k0 = 0; k0 < Kd; k0 += 32) {
        if (a_mode == 1) {
            int mm = tid & 63;
#pragma unroll
            for (int j = 0; j < 8; ++j) {
                int kk = (tid >> 6) + 4 * j;
                As[kk][mm] = A[abase[0] + (long long)(k0 + kk) * 2048];
            }
        } else {
            int kk = tid & 31;
#pragma unroll
            for (int j = 0; j < 8; ++j) {
                int mm = (tid >> 5) + 8 * j;
                As[kk][mm] = Ab[abase[j] + k0 + kk];
            }
        }
#pragma unroll
        for (int j = 0; j < 8; ++j) {
            int kk = (tid >> 6) + 4 * j;
            Bs[kk][nn_b] = Bb[(long long)(k0 + kk) * N + (n0 + nn_b)];
        }
        __syncthreads();
#pragma unroll
        for (int kk = 0; kk < 32; ++kk) {
            float av[4], bv[4];
#pragma unroll
            for (int x = 0; x < 4; ++x) av[x] = As[kk][tm * 4 + x];
#pragma unroll
            for (int y = 0; y < 4; ++y) bv[y] = Bs[kk][tn * 4 + y];
#pragma unroll
            for (int x = 0; x < 4; ++x)
#pragma unroll
                for (int y = 0; y < 4; ++y) acc[x][y] += av[x] * bv[y];
        }
        __syncthreads();
    }

#pragma unroll
    for (int x = 0; x < 4; ++x) {
        int row = m0 + tm * 4 + x;
#pragma unroll
        for (int y = 0; y < 4; ++y) {
            int n = n0 + tn * 4 + y;
            float v = acc[x][y];
            if (bias_mode == 1) v += bias[row];
            else if (bias_mode == 2) v += bias[n];
            long long ci;
            if (c_mode == 0) ci = (long long)bb * sC + (long long)row * N + n;
            else {
                int b2 = row / cR, r = row - b2 * cR;
                ci = ((long long)b2 * N + n) * cR + r;
            }
            if (resid) v += resid[ci];
            Cm[ci] = v;
        }
    }
}

// ---------------- bf16 MFMA GEMM: C(MxN) = A16(MxK) * BT16(NxK)^T ----------------
__global__ __launch_bounds__(256) void mfma_gemm_k(
    const ushort* __restrict__ A16, const ushort* __restrict__ BT16,
    float* __restrict__ C, ushort* __restrict__ C16,
    const float* __restrict__ bias,
    int M, int N, int K, int out16)
{
    __shared__ ushort As[128][40];
    __shared__ ushort Bs[128][40];
    int m0 = blockIdx.y * 128, n0 = blockIdx.x * 128;
    int tid = threadIdx.x;
    int wave = tid >> 6, lane = tid & 63;
    int wm = (wave & 1) * 64, wn = (wave >> 1) * 64;
    int l15 = lane & 15, lhi = lane >> 4;
    f32x4 acc[4][4] = {};
    int rs = tid >> 2, qs = tid & 3;

    for (int k0 = 0; k0 < K; k0 += 32) {
        *(uint4*)&As[rs][qs * 8]      = *(const uint4*)(A16 + (long long)(m0 + rs) * K + k0 + qs * 8);
        *(uint4*)&As[rs + 64][qs * 8] = *(const uint4*)(A16 + (long long)(m0 + rs + 64) * K + k0 + qs * 8);
        *(uint4*)&Bs[rs][qs * 8]      = *(const uint4*)(BT16 + (long long)(n0 + rs) * K + k0 + qs * 8);
        *(uint4*)&Bs[rs + 64][qs * 8] = *(const uint4*)(BT16 + (long long)(n0 + rs + 64) * K + k0 + qs * 8);
        __syncthreads();
        bf16x8 af[4], bfr[4];
#pragma unroll
        for (int fr = 0; fr < 4; ++fr)
            af[fr] = *(const bf16x8*)&As[wm + fr * 16 + l15][lhi * 8];
#pragma unroll
        for (int fc = 0; fc < 4; ++fc)
            bfr[fc] = *(const bf16x8*)&Bs[wn + fc * 16 + l15][lhi * 8];
#pragma unroll
        for (int fr = 0; fr < 4; ++fr)
#pragma unroll
            for (int fc = 0; fc < 4; ++fc)
                acc[fr][fc] = __builtin_amdgcn_mfma_f32_16x16x32_bf16(af[fr], bfr[fc], acc[fr][fc], 0, 0, 0);
        __syncthreads();
    }
#pragma unroll
    for (int fr = 0; fr < 4; ++fr) {
#pragma unroll
        for (int fc = 0; fc < 4; ++fc) {
            int col = n0 + wn + fc * 16 + l15;
            float bv = bias ? bias[col] : 0.f;
#pragma unroll
            for (int r = 0; r < 4; ++r) {
                int row = m0 + wm + fr * 16 + lhi * 4 + r;
                float v = acc[fr][fc][r] + bv;
                long long ci = (long long)row * N + col;
                if (out16) C16[ci] = f2b(v);
                else       C[ci] = v;
            }
        }
    }
}

// ---------------- bf16 MFMA implicit GEMM over NCHW f32 activations ----------------
// Y[((b*N+n)*P+p)] = bias[n] + sum_k WT[n*K+k] * X[((b*K+k)*P+p)]
template<int BN>
__global__ __launch_bounds__(256) void mfma_nchw_k(
    const float* __restrict__ X, const ushort* __restrict__ WT,
    const float* __restrict__ bias, float* __restrict__ Y,
    int P, int N, int K)
{
    constexpr int FC = BN / 32;
    __shared__ ushort As[128][40];
    int p0 = blockIdx.x * 128;
    int n0 = blockIdx.y * BN;
    int b  = blockIdx.z;
    int tid = threadIdx.x, wave = tid >> 6, lane = tid & 63;
    int l15 = lane & 15, lhi = lane >> 4;
    int wm = (wave & 1) * 64, wn = (wave >> 1) * (BN / 2);
    f32x4 acc[4][FC] = {};
    const float* Xb = X + (long long)b * K * P;
    int kk_s = tid >> 3, pq_s = tid & 7;

    for (int k0 = 0; k0 < K; k0 += 32) {
        const float* xr = Xb + (long long)(k0 + kk_s) * P + p0;
#pragma unroll
        for (int j = 0; j < 4; ++j) {
            float4 v = *(const float4*)(xr + j * 32 + pq_s * 4);
            int pp = j * 32 + pq_s * 4;
            As[pp][kk_s]     = f2b(v.x);
            As[pp + 1][kk_s] = f2b(v.y);
            As[pp + 2][kk_s] = f2b(v.z);
            As[pp + 3][kk_s] = f2b(v.w);
        }
        __syncthreads();
        bf16x8 af[4], bfr[FC];
#pragma unroll
        for (int fr = 0; fr < 4; ++fr)
            af[fr] = *(const bf16x8*)&As[wm + fr * 16 + l15][lhi * 8];
#pragma unroll
        for (int fc = 0; fc < FC; ++fc)
            bfr[fc] = *(const bf16x8*)(WT + (long long)(n0 + wn + fc * 16 + l15) * K + k0 + lhi * 8);
#pragma unroll
        for (int fr = 0; fr < 4; ++fr)
#pragma unroll
            for (int fc = 0; fc < FC; ++fc)
                acc[fr][fc] = __builtin_amdgcn_mfma_f32_16x16x32_bf16(af[fr], bfr[fc], acc[fr][fc], 0, 0, 0);
        __syncthreads();
    }
#pragma unroll
    for (int fc = 0; fc < FC; ++fc) {
        int n = n0 + wn + fc * 16 + l15;
        float bv = bias[n];
        float* yr = Y + ((long long)(b * N + n)) * P + p0 + wm + lhi * 4;
#pragma unroll
        for (int fr = 0; fr < 4; ++fr) {
            float4 o;
            o.x = acc[fr][fc][0] + bv;
            o.y = acc[fr][fc][1] + bv;
            o.z = acc[fr][fc][2] + bv;
            o.w = acc[fr][fc][3] + bv;
            *(float4*)(yr + fr * 16) = o;
        }
    }
}

__global__ void pack_w16_k(const float* __restrict__ W, ushort* __restrict__ O, int n)
{
    int gid = blockIdx.x * blockDim.x + threadIdx.x;
    if (gid < n) O[gid] = f2b(W[gid]);
}

// ---------------- MFMA flash attention (dh=16, 4 heads) ----------------
// block: (qtile 128, head, batch); 4 waves x 32 queries.
__global__ __launch_bounds__(256) void attn_mfma_k(const float* __restrict__ qkv,
                                                   float* __restrict__ out)
{
    __shared__ ushort Qs[128][40];   // [q][k(dh padded 32)]
    __shared__ ushort Ks[64][40];    // [key][k]
    __shared__ ushort VsT[16][72];   // [d][key]
    __shared__ ushort Ps[128][72];   // [q][key]
    int qt = blockIdx.x, h = blockIdx.y, b = blockIdx.z;
    int tid = threadIdx.x, wave = tid >> 6, lane = tid & 63;
    int l15 = lane & 15, lhi = lane >> 4;
    int q0 = wave * 32;

    // zero the k>=16 pads once (MFMA B operand must be 0 there; A side must be non-NaN)
    for (int i = tid; i < 1024; i += 256) {
        int row = i >> 3, c = i & 7;
        *(unsigned*)&Qs[row][16 + c * 2] = 0u;
    }
    for (int i = tid; i < 512; i += 256) {
        int row = i >> 3, c = i & 7;
        *(unsigned*)&Ks[row][16 + c * 2] = 0u;
    }
    {   // stage Q (scaled by 1/sqrt(16))
        const float* qp = qkv + ((long long)(b * P4 + qt * 128)) * 192 + h * 16;
        for (int i = tid; i < 2048; i += 256) {
            int row = i >> 4, d = i & 15;
            Qs[row][d] = f2b(qp[row * 192 + d] * 0.25f);
        }
    }
    __syncthreads();

    float mmax[2] = {-1e30f, -1e30f};
    float lsum[2] = {0.f, 0.f};
    f32x4 oacc[2] = {};   // [fc][r]: q=l15+fc*16+q0, d=lhi*4+r

    for (int k0 = 0; k0 < P4; k0 += 64) {
        const float* kp = qkv + ((long long)(b * P4 + k0)) * 192 + 64 + h * 16;
        for (int i = tid; i < 1024; i += 256) {
            int key = i >> 4, d = i & 15;
            Ks[key][d]  = f2b(kp[key * 192 + d]);
            VsT[d][key] = f2b(kp[key * 192 + 64 + d]);
        }
        __syncthreads();

        // S^T tile: rows=keys(64, fr 0..3), cols=q(32, fc 0..1)
        bf16x8 bq[2];
        bq[0] = *(const bf16x8*)&Qs[q0 + l15][lhi * 8];
        bq[1] = *(const bf16x8*)&Qs[q0 + 16 + l15][lhi * 8];
        f32x4 s[4][2];
#pragma unroll
        for (int fr = 0; fr < 4; ++fr) {
            bf16x8 ak = *(const bf16x8*)&Ks[fr * 16 + l15][lhi * 8];
            f32x4 z = {};
            s[fr][0] = __builtin_amdgcn_mfma_f32_16x16x32_bf16(ak, bq[0], z, 0, 0, 0);
            s[fr][1] = __builtin_amdgcn_mfma_f32_16x16x32_bf16(ak, bq[1], z, 0, 0, 0);
        }
        // online softmax over keys
#pragma unroll
        for (int fc = 0; fc < 2; ++fc) {
            float m = s[0][fc][0];
#pragma unroll
            for (int fr = 0; fr < 4; ++fr)
#pragma unroll
                for (int r = 0; r < 4; ++r) m = fmaxf(m, s[fr][fc][r]);
            m = fmaxf(m, __shfl_xor(m, 16));
            m = fmaxf(m, __shfl_xor(m, 32));
            float nm = fmaxf(mmax[fc], m);
            float corr = __expf(mmax[fc] - nm);
            mmax[fc] = nm;
            float ps = 0.f;
#pragma unroll
            for (int fr = 0; fr < 4; ++fr)
#pragma unroll
                for (int r = 0; r < 4; ++r) {
                    float p = __expf(s[fr][fc][r] - nm);
                    s[fr][fc][r] = p;
                    ps += p;
                }
            lsum[fc] = lsum[fc] * corr + ps;
#pragma unroll
            for (int r = 0; r < 4; ++r) oacc[fc][r] *= corr;
        }
        // write P (bf16) to wave-private Ps rows
#pragma unroll
        for (int fc = 0; fc < 2; ++fc)
#pragma unroll
            for (int fr = 0; fr < 4; ++fr) {
                uint2 pk;
                pk.x = cvtpk_bf16(s[fr][fc][0], s[fr][fc][1]);
                pk.y = cvtpk_bf16(s[fr][fc][2], s[fr][fc][3]);
                *(uint2*)&Ps[q0 + fc * 16 + l15][fr * 16 + lhi * 4] = pk;
            }
        // PV: O^T[d][q] += sum_key VsT[d][key] * Ps[q][key]
#pragma unroll
        for (int ks = 0; ks < 2; ++ks) {
            bf16x8 av = *(const bf16x8*)&VsT[l15][ks * 32 + lhi * 8];
#pragma unroll
            for (int fc = 0; fc < 2; ++fc) {
                bf16x8 bp = *(const bf16x8*)&Ps[q0 + fc * 16 + l15][ks * 32 + lhi * 8];
                oacc[fc] = __builtin_amdgcn_mfma_f32_16x16x32_bf16(av, bp, oacc[fc], 0, 0, 0);
            }
        }
        __syncthreads();
    }
#pragma unroll
    for (int fc = 0; fc < 2; ++fc) {
        float L = lsum[fc];
        L += __shfl_xor(L, 16);
        L += __shfl_xor(L, 32);
        float inv = 1.f / L;
        int q = qt * 128 + q0 + fc * 16 + l15;
        float* op = out + ((long long)(b * P4 + q)) * 64 + h * 16 + lhi * 4;
#pragma unroll
        for (int r = 0; r < 4; ++r) op[r] = oacc[fc][r] * inv;
    }
}

// ---------------- convT(1,8) tap-reduce ----------------
__global__ void convt_reduce_k(const float* __restrict__ Y, const float* __restrict__ bias,
                               const float* __restrict__ resid, float* __restrict__ out,
                               int NS, int L, int FO, int swap)
{
    int gid = blockIdx.x * blockDim.x + threadIdx.x;
    int total = BB * 64 * NS * FO;
    if (gid >= total) return;
    int d = gid & 63; int rest = gid >> 6;
    int p = rest % FO; rest /= FO;
    int s = rest % NS; int b = rest / NS;
    float v = bias[d];
    long long ybase = ((long long)(b * NS + s)) * L;
#pragma unroll
    for (int tap = 0; tap < 8; ++tap) {
        int l = p + tap - 7;
        if (l >= 0 && l < L) v += Y[(ybase + l) * 512 + tap * 64 + d];
    }
    long long oi = swap ? (((long long)(b * 64 + d) * FO + p) * NS + s)
                        : (((long long)(b * 64 + d) * NS + s) * FO + p);
    out[oi] = v + resid[oi];
}

// ---------------- 3x3 stride2 pad1 conv + ReLU, LDS-tiled ----------------
__global__ __launch_bounds__(256) void down_tile_k(const float* __restrict__ in,
    const float* __restrict__ w, const float* __restrict__ bias,
    float* __restrict__ out, int Hi, int Wi)
{
    int Ho = Hi >> 1, Wo = Wi >> 1;
    int ntx = Wo >> 3, nty = Ho >> 3;
    int tx = blockIdx.x % ntx; int rest = blockIdx.x / ntx;
    int ty = rest % nty; int b = rest / nty;
    int y0 = ty * 8, x0 = tx * 8;
    __shared__ float Ws[64][9];
    __shared__ float Is[17][21];
    int tid = threadIdx.x;
    int tm = tid >> 4, tn = tid & 15;
    float acc[4][4];
#pragma unroll
    for (int i = 0; i < 4; ++i)
#pragma unroll
        for (int j = 0; j < 4; ++j) acc[i][j] = 0.f;

    const float* ib = in + (long long)b * 64 * Hi * Wi;
    for (int c = 0; c < 64; ++c) {
        for (int idx = tid; idx < 576; idx += 256) {
            int d = idx / 9, t = idx - d * 9;
            Ws[d][t] = w[((d << 6) + c) * 9 + t];
        }
        const float* icp = ib + (long long)c * Hi * Wi;
        for (int idx = tid; idx < 289; idx += 256) {
            int r = idx / 17, s = idx - r * 17;
            int iy = 2 * y0 - 1 + r, ix = 2 * x0 - 1 + s;
            float v = 0.f;
            if (iy >= 0 && iy < Hi && ix >= 0 && ix < Wi) v = icp[(long long)iy * Wi + ix];
            Is[r][s] = v;
        }
        __syncthreads();
        float wr[4][9];
#pragma unroll
        for (int dd = 0; dd < 4; ++dd)
#pragma unroll
            for (int t = 0; t < 9; ++t) wr[dd][t] = Ws[tm * 4 + dd][t];
#pragma unroll
        for (int pp = 0; pp < 4; ++pp) {
            int p = tn * 4 + pp; int py = p >> 3, px = p & 7;
            float iv[9];
#pragma unroll
            for (int kh = 0; kh < 3; ++kh)
#pragma unroll
                for (int kw = 0; kw < 3; ++kw)
                    iv[kh * 3 + kw] = Is[2 * py + kh][2 * px + kw];
#pragma unroll
            for (int dd = 0; dd < 4; ++dd)
#pragma unroll
                for (int t = 0; t < 9; ++t) acc[dd][pp] += wr[dd][t] * iv[t];
        }
        __syncthreads();
    }
#pragma unroll
    for (int dd = 0; dd < 4; ++dd) {
        int d = tm * 4 + dd;
        float bsv = bias[d];
#pragma unroll
        for (int pp = 0; pp < 4; ++pp) {
            int p = tn * 4 + pp; int py = p >> 3, px = p & 7;
            out[(((long long)b * 64 + d) * Ho + (y0 + py)) * Wo + (x0 + px)] =
                fmaxf(acc[dd][pp] + bsv, 0.f);
        }
    }
}

// ---------------- unfolds -> bf16 ----------------
__global__ void unfold_freq_k(const float* __restrict__ ag, ushort* __restrict__ u)
{
    long long gid = (long long)blockIdx.x * blockDim.x + threadIdx.x;
    if (gid >= (long long)MF * II) return;
    int ch = (int)(gid & 511); int row = (int)(gid >> 9);
    int b = row / (T4 * LF); int rem = row - b * (T4 * LF);
    int t = rem / LF; int l = rem - t * LF;
    int d = ch >> 3, i = ch & 7;
    u[gid] = f2b(ag[((long long)((b * DD + d) * T4 + t)) * F4 + l + i]);
}
__global__ void unfold_time_k(const float* __restrict__ ag, ushort* __restrict__ u)
{
    long long gid = (long long)blockIdx.x * blockDim.x + threadIdx.x;
    if (gid >= (long long)MT * II) return;
    int ch = (int)(gid & 511); int row = (int)(gid >> 9);
    int b = row / (F4 * LT); int rem = row - b * (F4 * LT);
    int tt = rem / LT; int l = rem - tt * LT;
    int d = ch >> 3, i = ch & 7;
    u[gid] = f2b(ag[((long long)((b * DD + d) * T4 + (l + i))) * F4 + tt]);
}

// ---------------- weight packing (transposed, bf16) ----------------
__global__ void pack_wcatT_k(const float* __restrict__ Wx, const float* __restrict__ Whw,
                             ushort* __restrict__ WT)
{
    int gid = blockIdx.x * blockDim.x + threadIdx.x;
    if (gid >= 1024 * 512) return;
    int k = gid & 511; int n = gid >> 9;
    int dir = n >> 9; int c = n & 511;
    float v = (c < 384) ? Wx[(dir * 512 + k) * 384 + c]
                        : Whw[(dir * 512 + k) * 128 + (c - 384)];
    WT[gid] = f2b(v);
}
__global__ void pack_pwT_k(const float* __restrict__ pw, ushort* __restrict__ WT)
{
    int gid = blockIdx.x * blockDim.x + threadIdx.x;
    if (gid >= 512 * 256) return;
    int k = gid & 255; int n = gid >> 8;
    WT[gid] = f2b(pw[k * 512 + n]);
}
__global__ void pack_wct2T_k(const float* __restrict__ ctw, ushort* __restrict__ WT)
{
    int gid = blockIdx.x * blockDim.x + threadIdx.x;
    if (gid >= 512 * 512) return;
    int k = gid & 511; int n = gid >> 9;
    int tap = n >> 6, d = n & 63;
    WT[gid] = f2b(ctw[((d * 512) + k) * 8 + tap]);
}

// ---------------- SRU elementwise recurrence (G f32 -> h bf16) ----------------
__global__ void sru_scan_k(const float* __restrict__ G, const float* __restrict__ bfw,
                           const float* __restrict__ brw, ushort* __restrict__ hout,
                           int Nn, int L)
{
    int gid = blockIdx.x * blockDim.x + threadIdx.x;
    if (gid >= Nn * 256) return;
    int h = gid & 127; int dir = (gid >> 7) & 1; int n = gid >> 8;
    const float bf = bfw[dir * 128 + h], br = brw[dir * 128 + h];
    int base = dir * 512 + h;
    float c = 0.f;
    for (int s = 0; s < L; ++s) {
        int l = dir ? (L - 1 - s) : s;
        const float* g = G + ((long long)(n * L + l)) * 1024 + base;
        float xt = g[0];
        float fv = 1.f / (1.f + __expf(-(g[128] + bf)));
        float rv = 1.f / (1.f + __expf(-(g[256] + br)));
        float xh = g[384];
        c = fv * c + (1.f - fv) * xt;
        float hv = rv * c + (1.f - rv) * xh;
        hout[((long long)(n * L + l)) * 256 + dir * 128 + h] = f2b(hv);
    }
}

// ---------------- convT k=2 s=2 + residual ----------------
__global__ void up_k(const float* __restrict__ in, const float* __restrict__ w,
                     const float* __restrict__ bias, const float* __restrict__ resid,
                     float* __restrict__ out, int Hi, int Wi)
{
    int Ho = Hi * 2, Wo = Wi * 2;
    long long gid = (long long)blockIdx.x * blockDim.x + threadIdx.x;
    long long total = (long long)BB * DD * Ho * Wo;
    if (gid >= total) return;
    int x = (int)(gid % Wo); long long t1 = gid / Wo;
    int y = (int)(t1 % Ho); long long t2 = t1 / Ho;
    int d = (int)(t2 & 63); int b = (int)(t2 >> 6);
    int kh = 1 - (y & 1), kw = 1 - (x & 1);
    int iy = y >> 1, ix = x >> 1;
    float acc = bias[d];
    const float* ip = in + (long long)b * DD * Hi * Wi + (long long)iy * Wi + ix;
    const float* wp = w + d * DD * 4 + kh * 2 + kw;
    for (int c = 0; c < DD; ++c) acc += ip[(long long)c * Hi * Wi] * wp[c * 4];
    out[gid] = acc + resid[gid];
}

// ---------------- host launch ----------------
extern "C" void kernel_launch(void* const* d_in, const int* in_sizes, int n_in,
                              void* d_out, int out_size, void* d_ws, size_t ws_size,
                              hipStream_t stream)
{
    const float* A_in  = (const float*)d_in[0];
    const float* cw    = (const float*)d_in[1];
    const float* cb    = (const float*)d_in[2];
    const float* dw0   = (const float*)d_in[3];
    const float* db0   = (const float*)d_in[4];
    const float* dw1   = (const float*)d_in[5];
    const float* db1   = (const float*)d_in[6];
    const float* f_Wx  = (const float*)d_in[7];
    const float* f_bf  = (const float*)d_in[8];
    const float* f_br  = (const float*)d_in[9];
    const float* f_Whw = (const float*)d_in[10];
    const float* f_pw  = (const float*)d_in[11];
    const float* f_pb  = (const float*)d_in[12];
    const float* f_ctw = (const float*)d_in[13];
    const float* f_ctb = (const float*)d_in[14];
    const float* t_Wx  = (const float*)d_in[15];
    const float* t_bf  = (const float*)d_in[16];
    const float* t_br  = (const float*)d_in[17];
    const float* t_Whw = (const float*)d_in[18];
    const float* t_pw  = (const float*)d_in[19];
    const float* t_pb  = (const float*)d_in[20];
    const float* t_ctw = (const float*)d_in[21];
    const float* t_ctb = (const float*)d_in[22];
    const float* qkv_w = (const float*)d_in[23];
    const float* qkv_b = (const float*)d_in[24];
    const float* ow    = (const float*)d_in[25];
    const float* ob    = (const float*)d_in[26];
    const float* upw0  = (const float*)d_in[27];
    const float* upb0  = (const float*)d_in[28];
    const float* upw1  = (const float*)d_in[29];
    const float* upb1  = (const float*)d_in[30];
    const float* fw    = (const float*)d_in[31];
    const float* fb    = (const float*)d_in[32];

    float* ws  = (float*)d_ws;
    float* out = (float*)d_out;

    // workspace layout (f32 units)
    float* ag    = ws + 0;          // 1,048,576
    float* x1    = ws + 1048576;    // 4,194,304
    float* Ureg  = ws + 5242880;    // 7,471,104 : u16 / Y / y1
    float* G     = ws + 12713984;   // 14,942,208 (later y0)
    float* h16f  = ws + 27656192;   // h bf16
    float* z16f  = ws + 29523968;   // z bf16
    float* wcatf = ws + 33259520;   // WcatT bf16
    float* wct2f = ws + 33521664;   // Wct2T bf16
    float* pwtf  = ws + 33652736;   // pwT bf16
    float* fout  = ws + 33718272;
    float* tout  = ws + 34766848;
    float* qkvb  = ws + 35815424;
    float* attnO = ws + 38961152;
    float* dp    = ws + 40009728;
    float* cw16f = ws + 41058304;   // 8192 (cw bf16: 16384 ushorts)
    float* fw16f = ws + 41066496;   // 8192 (fw bf16)
    ushort* u16    = (ushort*)Ureg;
    float*  Y      = Ureg;
    float*  y1     = Ureg;
    float*  y0     = G;
    ushort* h16    = (ushort*)h16f;
    ushort* z16    = (ushort*)z16f;
    ushort* WcatT  = (ushort*)wcatf;
    ushort* Wct2T  = (ushort*)wct2f;
    ushort* pwT    = (ushort*)pwtf;
    ushort* cw16   = (ushort*)cw16f;
    ushort* fw16   = (ushort*)fw16f;
    float*  x0     = out;           // x0 parked in d_out

    dim3 blk(256);

    // 1. compress (bf16 MFMA implicit GEMM over NCHW)
    pack_w16_k<<<dim3(64), blk, 0, stream>>>(cw, cw16, 16384);
    pack_w16_k<<<dim3(64), blk, 0, stream>>>(fw, fw16, 16384);
    mfma_nchw_k<64><<<dim3(256, 1, 8), blk, 0, stream>>>(A_in, cw16, cb, x0, 32768, 64, 256);

    // 2-3. downsample
    down_tile_k<<<dim3(1024), blk, 0, stream>>>(x0, dw0, db0, x1, TT, FF);
    down_tile_k<<<dim3(256), blk, 0, stream>>>(x1, dw1, db1, ag, T2, F2);

    // ---- frequency pathway ----
    unfold_freq_k<<<dim3((MF * II) / 256), blk, 0, stream>>>(ag, u16);
    pack_wcatT_k<<<dim3(2048), blk, 0, stream>>>(f_Wx, f_Whw, WcatT);
    mfma_gemm_k<<<dim3(8, MF / 128), blk, 0, stream>>>(u16, WcatT, G, nullptr, nullptr,
        MF, 1024, 512, 0);
    sru_scan_k<<<dim3(131072 / 256), blk, 0, stream>>>(G, f_bf, f_br, h16, 512, LF);
    pack_pwT_k<<<dim3(512), blk, 0, stream>>>(f_pw, pwT);
    mfma_gemm_k<<<dim3(4, MF / 128), blk, 0, stream>>>(h16, pwT, nullptr, z16, f_pb,
        MF, 512, 256, 1);
    pack_wct2T_k<<<dim3(1024), blk, 0, stream>>>(f_ctw, Wct2T);
    mfma_gemm_k<<<dim3(4, MF / 128), blk, 0, stream>>>(z16, Wct2T, Y, nullptr, nullptr,
        MF, 512, 512, 0);
    convt_reduce_k<<<dim3(4096), blk, 0, stream>>>(Y, f_ctb, ag, fout, 64, LF, 32, 0);

    // ---- time pathway ----
    unfold_time_k<<<dim3((MT * II) / 256), blk, 0, stream>>>(ag, u16);
    pack_wcatT_k<<<dim3(2048), blk, 0, stream>>>(t_Wx, t_Whw, WcatT);
    mfma_gemm_k<<<dim3(8, MT / 128), blk, 0, stream>>>(u16, WcatT, G, nullptr, nullptr,
        MT, 1024, 512, 0);
    sru_scan_k<<<dim3(65536 / 256), blk, 0, stream>>>(G, t_bf, t_br, h16, 256, LT);
    pack_pwT_k<<<dim3(512), blk, 0, stream>>>(t_pw, pwT);
    mfma_gemm_k<<<dim3(4, MT / 128), blk, 0, stream>>>(h16, pwT, nullptr, z16, t_pb,
        MT, 512, 256, 1);
    pack_wct2T_k<<<dim3(1024), blk, 0, stream>>>(t_ctw, Wct2T);
    mfma_gemm_k<<<dim3(4, MT / 128), blk, 0, stream>>>(z16, Wct2T, Y, nullptr, nullptr,
        MT, 512, 512, 0);
    convt_reduce_k<<<dim3(4096), blk, 0, stream>>>(Y, t_ctb, fout, tout, 32, LT, 64, 1);

    // ---- attention ----
    gemm_k<<<dim3(3, 256, 1), blk, 0, stream>>>(tout, qkv_w, qkvb, qkv_b, nullptr,
        16384, 192, 64, 0LL, 0LL, 0LL, 2, 1, 0, 0);
    attn_mfma_k<<<dim3(16, NHEADS, BB), blk, 0, stream>>>(qkvb, attnO);
    gemm_k<<<dim3(1, 256, 1), blk, 0, stream>>>(attnO, ow, dp, ob, tout,
        16384, 64, 64, 0LL, 0LL, 0LL, 2, 0, 1, 2048);

    // ---- reconstruction ----
    up_k<<<dim3(4194304 / 256), blk, 0, stream>>>(dp, upw0, upb0, x1, y1, T4, F4);
    up_k<<<dim3(16777216 / 256), blk, 0, stream>>>(y1, upw1, upb1, x0, y0, T2, F2);

    // final 1x1 conv (bf16 MFMA implicit GEMM)
    mfma_nchw_k<128><<<dim3(256, 2, 8), blk, 0, stream>>>(y0, fw16, fb, out, 32768, 256, 64);
}

// Round 5
// 876.211 us; speedup vs baseline: 4.7298x; 1.2851x over previous
//
#include <hip/hip_runtime.h>

// ---------------- problem constants ----------------
#define BB 8
#define CC 256
#define TT 256
#define FF 128
#define DD 64
#define HH 128
#define NHEADS 4
#define KK 8
#define II 512            // D*K
#define T2 128
#define F2 64
#define T4 64
#define F4 32
#define P4 2048           // T4*F4

// freq pathway: N=512 seqs, L=25 ; time pathway: N=256 seqs, L=57
#define LF 25
#define LT 57
#define MF (512*LF)       // 12800
#define MT (256*LT)       // 14592

typedef __attribute__((ext_vector_type(8))) short bf16x8;
typedef __attribute__((ext_vector_type(4))) float f32x4;

__device__ __forceinline__ ushort f2b(float x) {
    unsigned u = __float_as_uint(x);
    unsigned r = (u + 0x7FFFu + ((u >> 16) & 1u)) >> 16;
    return (ushort)r;
}
__device__ __forceinline__ float b2f(ushort x) {
    return __uint_as_float(((unsigned)x) << 16);
}
__device__ __forceinline__ unsigned cvtpk_bf16(float lo, float hi) {
    unsigned r;
    asm("v_cvt_pk_bf16_f32 %0, %1, %2" : "=v"(r) : "v"(lo), "v"(hi));
    return r;
}

// ---------------- bf16 MFMA GEMM: C(MxN) = A16(MxK) * BT16(NxK)^T ----------------
__global__ __launch_bounds__(256) void mfma_gemm_k(
    const ushort* __restrict__ A16, const ushort* __restrict__ BT16,
    float* __restrict__ C, ushort* __restrict__ C16,
    const float* __restrict__ bias,
    int M, int N, int K, int out16)
{
    __shared__ ushort As[128][40];
    __shared__ ushort Bs[128][40];
    int m0 = blockIdx.y * 128, n0 = blockIdx.x * 128;
    int tid = threadIdx.x;
    int wave = tid >> 6, lane = tid & 63;
    int wm = (wave & 1) * 64, wn = (wave >> 1) * 64;
    int l15 = lane & 15, lhi = lane >> 4;
    f32x4 acc[4][4] = {};
    int rs = tid >> 2, qs = tid & 3;

    for (int k0 = 0; k0 < K; k0 += 32) {
        *(uint4*)&As[rs][qs * 8]      = *(const uint4*)(A16 + (long long)(m0 + rs) * K + k0 + qs * 8);
        *(uint4*)&As[rs + 64][qs * 8] = *(const uint4*)(A16 + (long long)(m0 + rs + 64) * K + k0 + qs * 8);
        *(uint4*)&Bs[rs][qs * 8]      = *(const uint4*)(BT16 + (long long)(n0 + rs) * K + k0 + qs * 8);
        *(uint4*)&Bs[rs + 64][qs * 8] = *(const uint4*)(BT16 + (long long)(n0 + rs + 64) * K + k0 + qs * 8);
        __syncthreads();
        bf16x8 af[4], bfr[4];
#pragma unroll
        for (int fr = 0; fr < 4; ++fr)
            af[fr] = *(const bf16x8*)&As[wm + fr * 16 + l15][lhi * 8];
#pragma unroll
        for (int fc = 0; fc < 4; ++fc)
            bfr[fc] = *(const bf16x8*)&Bs[wn + fc * 16 + l15][lhi * 8];
#pragma unroll
        for (int fr = 0; fr < 4; ++fr)
#pragma unroll
            for (int fc = 0; fc < 4; ++fc)
                acc[fr][fc] = __builtin_amdgcn_mfma_f32_16x16x32_bf16(af[fr], bfr[fc], acc[fr][fc], 0, 0, 0);
        __syncthreads();
    }
#pragma unroll
    for (int fr = 0; fr < 4; ++fr) {
#pragma unroll
        for (int fc = 0; fc < 4; ++fc) {
            int col = n0 + wn + fc * 16 + l15;
            float bv = bias ? bias[col] : 0.f;
#pragma unroll
            for (int r = 0; r < 4; ++r) {
                int row = m0 + wm + fr * 16 + lhi * 4 + r;
                float v = acc[fr][fc][r] + bv;
                long long ci = (long long)row * N + col;
                if (out16) C16[ci] = f2b(v);
                else       C[ci] = v;
            }
        }
    }
}

// ---------------- bf16 MFMA implicit GEMM over NCHW f32 activations ----------------
template<int BN>
__global__ __launch_bounds__(256) void mfma_nchw_k(
    const float* __restrict__ X, const ushort* __restrict__ WT,
    const float* __restrict__ bias, float* __restrict__ Y,
    int P, int N, int K)
{
    constexpr int FC = BN / 32;
    __shared__ ushort As[128][40];
    int p0 = blockIdx.x * 128;
    int n0 = blockIdx.y * BN;
    int b  = blockIdx.z;
    int tid = threadIdx.x, wave = tid >> 6, lane = tid & 63;
    int l15 = lane & 15, lhi = lane >> 4;
    int wm = (wave & 1) * 64, wn = (wave >> 1) * (BN / 2);
    f32x4 acc[4][FC] = {};
    const float* Xb = X + (long long)b * K * P;
    int kk_s = tid >> 3, pq_s = tid & 7;

    for (int k0 = 0; k0 < K; k0 += 32) {
        const float* xr = Xb + (long long)(k0 + kk_s) * P + p0;
#pragma unroll
        for (int j = 0; j < 4; ++j) {
            float4 v = *(const float4*)(xr + j * 32 + pq_s * 4);
            int pp = j * 32 + pq_s * 4;
            As[pp][kk_s]     = f2b(v.x);
            As[pp + 1][kk_s] = f2b(v.y);
            As[pp + 2][kk_s] = f2b(v.z);
            As[pp + 3][kk_s] = f2b(v.w);
        }
        __syncthreads();
        bf16x8 af[4], bfr[FC];
#pragma unroll
        for (int fr = 0; fr < 4; ++fr)
            af[fr] = *(const bf16x8*)&As[wm + fr * 16 + l15][lhi * 8];
#pragma unroll
        for (int fc = 0; fc < FC; ++fc)
            bfr[fc] = *(const bf16x8*)(WT + (long long)(n0 + wn + fc * 16 + l15) * K + k0 + lhi * 8);
#pragma unroll
        for (int fr = 0; fr < 4; ++fr)
#pragma unroll
            for (int fc = 0; fc < FC; ++fc)
                acc[fr][fc] = __builtin_amdgcn_mfma_f32_16x16x32_bf16(af[fr], bfr[fc], acc[fr][fc], 0, 0, 0);
        __syncthreads();
    }
#pragma unroll
    for (int fc = 0; fc < FC; ++fc) {
        int n = n0 + wn + fc * 16 + l15;
        float bv = bias[n];
        float* yr = Y + ((long long)(b * N + n)) * P + p0 + wm + lhi * 4;
#pragma unroll
        for (int fr = 0; fr < 4; ++fr) {
            float4 o;
            o.x = acc[fr][fc][0] + bv;
            o.y = acc[fr][fc][1] + bv;
            o.z = acc[fr][fc][2] + bv;
            o.w = acc[fr][fc][3] + bv;
            *(float4*)(yr + fr * 16) = o;
        }
    }
}

// ---------------- convT k=2 s=2 as MFMA: O[p][parity*64+d] = sum_c in[c,p]*w[c,d,1-py,1-px] ----------------
// grid: (P/128, 2, BB); n0 = blockIdx.y*128 covers parities {0,1} / {2,3}
__global__ __launch_bounds__(256) void up_mfma_k(
    const float* __restrict__ in, const ushort* __restrict__ WT,
    const float* __restrict__ bias, const float* __restrict__ resid,
    float* __restrict__ out, int P, int wsh /*log2 Wi*/)
{
    __shared__ ushort As[128][72];
    int p0 = blockIdx.x * 128;
    int n0 = blockIdx.y * 128;
    int b  = blockIdx.z;
    int tid = threadIdx.x, wave = tid >> 6, lane = tid & 63;
    int l15 = lane & 15, lhi = lane >> 4;
    int wm = (wave & 1) * 64, wn = (wave >> 1) * 64;
    int Wi = 1 << wsh;
    int Ho = ((P >> wsh) << 1), Wo = Wi << 1;

    int kk_s = tid >> 3, pq_s = tid & 7;
#pragma unroll
    for (int h = 0; h < 2; ++h) {
        int k = h * 32 + kk_s;
        const float* xr = in + ((long long)(b * 64 + k)) * P + p0 + pq_s * 16;
#pragma unroll
        for (int j = 0; j < 4; ++j) {
            float4 v = *(const float4*)(xr + j * 4);
            int pp = pq_s * 16 + j * 4;
            As[pp][k]     = f2b(v.x);
            As[pp + 1][k] = f2b(v.y);
            As[pp + 2][k] = f2b(v.z);
            As[pp + 3][k] = f2b(v.w);
        }
    }
    __syncthreads();

    f32x4 acc[4][4] = {};
#pragma unroll
    for (int c = 0; c < 2; ++c) {
        bf16x8 af[4], bfr[4];
#pragma unroll
        for (int fr = 0; fr < 4; ++fr)
            af[fr] = *(const bf16x8*)&As[wm + fr * 16 + l15][c * 32 + lhi * 8];
#pragma unroll
        for (int fc = 0; fc < 4; ++fc)
            bfr[fc] = *(const bf16x8*)(WT + (long long)(n0 + wn + fc * 16 + l15) * 64 + c * 32 + lhi * 8);
#pragma unroll
        for (int fr = 0; fr < 4; ++fr)
#pragma unroll
            for (int fc = 0; fc < 4; ++fc)
                acc[fr][fc] = __builtin_amdgcn_mfma_f32_16x16x32_bf16(af[fr], bfr[fc], acc[fr][fc], 0, 0, 0);
    }

#pragma unroll
    for (int fc = 0; fc < 4; ++fc) {
        int n = n0 + wn + fc * 16 + l15;
        int parity = n >> 6, d = n & 63;
        int py = parity >> 1, px = parity & 1;
        float bv = bias[d];
        const long long obase = ((long long)(b * 64 + d)) * Ho * Wo;
#pragma unroll
        for (int fr = 0; fr < 4; ++fr) {
#pragma unroll
            for (int r = 0; r < 4; ++r) {
                int p = p0 + wm + fr * 16 + lhi * 4 + r;
                int iy = p >> wsh, ix = p & (Wi - 1);
                long long oi = obase + (long long)(2 * iy + py) * Wo + 2 * ix + px;
                out[oi] = acc[fr][fc][r] + bv + resid[oi];
            }
        }
    }
}

// ---------------- qkv projection: bf16 MFMA over NCHW tout -> bf16 [b][p][192] ----------------
__global__ __launch_bounds__(256) void mfma_qkv_k(
    const float* __restrict__ X, const ushort* __restrict__ WT,
    const float* __restrict__ bias, ushort* __restrict__ C16)
{
    __shared__ ushort As[128][72];
    int p0 = blockIdx.x * 128;
    int b  = blockIdx.z;
    int tid = threadIdx.x, wave = tid >> 6, lane = tid & 63;
    int l15 = lane & 15, lhi = lane >> 4;
    int wm = (wave & 1) * 64, wn = (wave >> 1) * 96;

    int kk_s = tid >> 3, pq_s = tid & 7;
#pragma unroll
    for (int h = 0; h < 2; ++h) {
        int k = h * 32 + kk_s;
        const float* xr = X + ((long long)(b * 64 + k)) * P4 + p0 + pq_s * 16;
#pragma unroll
        for (int j = 0; j < 4; ++j) {
            float4 v = *(const float4*)(xr + j * 4);
            int pp = pq_s * 16 + j * 4;
            As[pp][k]     = f2b(v.x);
            As[pp + 1][k] = f2b(v.y);
            As[pp + 2][k] = f2b(v.z);
            As[pp + 3][k] = f2b(v.w);
        }
    }
    __syncthreads();

    f32x4 acc[4][6] = {};
#pragma unroll
    for (int c = 0; c < 2; ++c) {
        bf16x8 af[4], bfr[6];
#pragma unroll
        for (int fr = 0; fr < 4; ++fr)
            af[fr] = *(const bf16x8*)&As[wm + fr * 16 + l15][c * 32 + lhi * 8];
#pragma unroll
        for (int fc = 0; fc < 6; ++fc)
            bfr[fc] = *(const bf16x8*)(WT + (long long)(wn + fc * 16 + l15) * 64 + c * 32 + lhi * 8);
#pragma unroll
        for (int fr = 0; fr < 4; ++fr)
#pragma unroll
            for (int fc = 0; fc < 6; ++fc)
                acc[fr][fc] = __builtin_amdgcn_mfma_f32_16x16x32_bf16(af[fr], bfr[fc], acc[fr][fc], 0, 0, 0);
    }
#pragma unroll
    for (int fc = 0; fc < 6; ++fc) {
        int n = wn + fc * 16 + l15;
        float bv = bias[n];
#pragma unroll
        for (int fr = 0; fr < 4; ++fr)
#pragma unroll
            for (int r = 0; r < 4; ++r) {
                int p = p0 + wm + fr * 16 + lhi * 4 + r;
                C16[((long long)(b * P4 + p)) * 192 + n] = f2b(acc[fr][fc][r] + bv);
            }
    }
}

// ---------------- attention out-proj: dp[(b*64+n)*2048+p] = attnO*ow + ob + tout ----------------
__global__ __launch_bounds__(256) void mfma_attnout_k(
    const float* __restrict__ A, const ushort* __restrict__ owT,
    const float* __restrict__ ob, const float* __restrict__ resid,
    float* __restrict__ dp)
{
    __shared__ ushort As[128][72];
    int p0 = blockIdx.x * 128;
    int b  = blockIdx.z;
    int tid = threadIdx.x, wave = tid >> 6, lane = tid & 63;
    int l15 = lane & 15, lhi = lane >> 4;
    int wm = (wave & 1) * 64, wn = (wave >> 1) * 32;

    int rs = tid >> 2, qs = tid & 3;
#pragma unroll
    for (int h = 0; h < 2; ++h) {
        int row = h * 64 + rs;
        const float* ar = A + ((long long)(b * P4 + p0 + row)) * 64 + qs * 16;
#pragma unroll
        for (int j = 0; j < 4; ++j) {
            float4 v = *(const float4*)(ar + j * 4);
            int c = qs * 16 + j * 4;
            *(unsigned*)&As[row][c]     = cvtpk_bf16(v.x, v.y);
            *(unsigned*)&As[row][c + 2] = cvtpk_bf16(v.z, v.w);
        }
    }
    __syncthreads();

    f32x4 acc[4][2] = {};
#pragma unroll
    for (int c = 0; c < 2; ++c) {
        bf16x8 af[4], bfr[2];
#pragma unroll
        for (int fr = 0; fr < 4; ++fr)
            af[fr] = *(const bf16x8*)&As[wm + fr * 16 + l15][c * 32 + lhi * 8];
#pragma unroll
        for (int fc = 0; fc < 2; ++fc)
            bfr[fc] = *(const bf16x8*)(owT + (long long)(wn + fc * 16 + l15) * 64 + c * 32 + lhi * 8);
#pragma unroll
        for (int fr = 0; fr < 4; ++fr)
#pragma unroll
            for (int fc = 0; fc < 2; ++fc)
                acc[fr][fc] = __builtin_amdgcn_mfma_f32_16x16x32_bf16(af[fr], bfr[fc], acc[fr][fc], 0, 0, 0);
    }
#pragma unroll
    for (int fc = 0; fc < 2; ++fc) {
        int n = wn + fc * 16 + l15;
        float bv = ob[n];
        long long base = ((long long)(b * 64 + n)) * P4;
#pragma unroll
        for (int fr = 0; fr < 4; ++fr) {
            int p = p0 + wm + fr * 16 + lhi * 4;
            float4 rv = *(const float4*)(resid + base + p);
            float4 o;
            o.x = acc[fr][fc][0] + bv + rv.x;
            o.y = acc[fr][fc][1] + bv + rv.y;
            o.z = acc[fr][fc][2] + bv + rv.z;
            o.w = acc[fr][fc][3] + bv + rv.w;
            *(float4*)(dp + base + p) = o;
        }
    }
}

__global__ void pack_w16_k(const float* __restrict__ W, ushort* __restrict__ O, int n)
{
    int gid = blockIdx.x * blockDim.x + threadIdx.x;
    if (gid < n) O[gid] = f2b(W[gid]);
}
// O[n*K+k] = W[k*N+n]
__global__ void pack_transposeT_k(const float* __restrict__ W, ushort* __restrict__ O,
                                  int K, int N)
{
    int gid = blockIdx.x * blockDim.x + threadIdx.x;
    if (gid >= K * N) return;
    int k = gid % K, n = gid / K;
    O[gid] = f2b(W[(long long)k * N + n]);
}
// up-conv weights: O[(parity*64+d)*64 + c] = w[d][c][1-py][1-px]  (w is [d][c][2][2])
__global__ void pack_upw_k(const float* __restrict__ w, ushort* __restrict__ O)
{
    int gid = blockIdx.x * blockDim.x + threadIdx.x;
    if (gid >= 16384) return;
    int c = gid & 63; int n = gid >> 6;
    int parity = n >> 6, d = n & 63;
    int py = parity >> 1, px = parity & 1;
    O[gid] = f2b(w[((d * 64 + c) * 2 + (1 - py)) * 2 + (1 - px)]);
}

// ---------------- MFMA flash attention (dh=16, 4 heads), bf16 qkv input ----------------
__global__ __launch_bounds__(256) void attn_mfma_k(const ushort* __restrict__ qkv,
                                                   float* __restrict__ out)
{
    __shared__ ushort Qs[128][40];   // [q][k(dh padded 32)]
    __shared__ ushort Ks[64][40];    // [key][k]
    __shared__ ushort VsT[16][72];   // [d][key]
    __shared__ ushort Ps[128][72];   // [q][key]
    int qt = blockIdx.x, h = blockIdx.y, b = blockIdx.z;
    int tid = threadIdx.x, wave = tid >> 6, lane = tid & 63;
    int l15 = lane & 15, lhi = lane >> 4;
    int q0 = wave * 32;

    for (int i = tid; i < 1024; i += 256) {
        int row = i >> 3, c = i & 7;
        *(unsigned*)&Qs[row][16 + c * 2] = 0u;
    }
    for (int i = tid; i < 512; i += 256) {
        int row = i >> 3, c = i & 7;
        *(unsigned*)&Ks[row][16 + c * 2] = 0u;
    }
    {   // stage Q (scaled by 1/sqrt(16))
        const ushort* qp = qkv + ((long long)(b * P4 + qt * 128)) * 192 + h * 16;
        for (int i = tid; i < 2048; i += 256) {
            int row = i >> 4, d = i & 15;
            Qs[row][d] = f2b(b2f(qp[row * 192 + d]) * 0.25f);
        }
    }
    __syncthreads();

    float mmax[2] = {-1e30f, -1e30f};
    float lsum[2] = {0.f, 0.f};
    f32x4 oacc[2] = {};

    for (int k0 = 0; k0 < P4; k0 += 64) {
        const ushort* kp = qkv + ((long long)(b * P4 + k0)) * 192 + 64 + h * 16;
        for (int i = tid; i < 1024; i += 256) {
            int key = i >> 4, d = i & 15;
            Ks[key][d]  = kp[key * 192 + d];
            VsT[d][key] = kp[key * 192 + 64 + d];
        }
        __syncthreads();

        bf16x8 bq[2];
        bq[0] = *(const bf16x8*)&Qs[q0 + l15][lhi * 8];
        bq[1] = *(const bf16x8*)&Qs[q0 + 16 + l15][lhi * 8];
        f32x4 s[4][2];
#pragma unroll
        for (int fr = 0; fr < 4; ++fr) {
            bf16x8 ak = *(const bf16x8*)&Ks[fr * 16 + l15][lhi * 8];
            f32x4 z = {};
            s[fr][0] = __builtin_amdgcn_mfma_f32_16x16x32_bf16(ak, bq[0], z, 0, 0, 0);
            s[fr][1] = __builtin_amdgcn_mfma_f32_16x16x32_bf16(ak, bq[1], z, 0, 0, 0);
        }
#pragma unroll
        for (int fc = 0; fc < 2; ++fc) {
            float m = s[0][fc][0];
#pragma unroll
            for (int fr = 0; fr < 4; ++fr)
#pragma unroll
                for (int r = 0; r < 4; ++r) m = fmaxf(m, s[fr][fc][r]);
            m = fmaxf(m, __shfl_xor(m, 16));
            m = fmaxf(m, __shfl_xor(m, 32));
            float nm = fmaxf(mmax[fc], m);
            float corr = __expf(mmax[fc] - nm);
            mmax[fc] = nm;
            float ps = 0.f;
#pragma unroll
            for (int fr = 0; fr < 4; ++fr)
#pragma unroll
                for (int r = 0; r < 4; ++r) {
                    float p = __expf(s[fr][fc][r] - nm);
                    s[fr][fc][r] = p;
                    ps += p;
                }
            lsum[fc] = lsum[fc] * corr + ps;
#pragma unroll
            for (int r = 0; r < 4; ++r) oacc[fc][r] *= corr;
        }
#pragma unroll
        for (int fc = 0; fc < 2; ++fc)
#pragma unroll
            for (int fr = 0; fr < 4; ++fr) {
                uint2 pk;
                pk.x = cvtpk_bf16(s[fr][fc][0], s[fr][fc][1]);
                pk.y = cvtpk_bf16(s[fr][fc][2], s[fr][fc][3]);
                *(uint2*)&Ps[q0 + fc * 16 + l15][fr * 16 + lhi * 4] = pk;
            }
#pragma unroll
        for (int ks = 0; ks < 2; ++ks) {
            bf16x8 av = *(const bf16x8*)&VsT[l15][ks * 32 + lhi * 8];
#pragma unroll
            for (int fc = 0; fc < 2; ++fc) {
                bf16x8 bp = *(const bf16x8*)&Ps[q0 + fc * 16 + l15][ks * 32 + lhi * 8];
                oacc[fc] = __builtin_amdgcn_mfma_f32_16x16x32_bf16(av, bp, oacc[fc], 0, 0, 0);
            }
        }
        __syncthreads();
    }
#pragma unroll
    for (int fc = 0; fc < 2; ++fc) {
        float L = lsum[fc];
        L += __shfl_xor(L, 16);
        L += __shfl_xor(L, 32);
        float inv = 1.f / L;
        int q = qt * 128 + q0 + fc * 16 + l15;
        float* op = out + ((long long)(b * P4 + q)) * 64 + h * 16 + lhi * 4;
#pragma unroll
        for (int r = 0; r < 4; ++r) op[r] = oacc[fc][r] * inv;
    }
}

// ---------------- convT(1,8) tap-reduce ----------------
__global__ void convt_reduce_k(const float* __restrict__ Y, const float* __restrict__ bias,
                               const float* __restrict__ resid, float* __restrict__ out,
                               int NS, int L, int FO, int swap)
{
    int gid = blockIdx.x * blockDim.x + threadIdx.x;
    int total = BB * 64 * NS * FO;
    if (gid >= total) return;
    int d = gid & 63; int rest = gid >> 6;
    int p = rest % FO; rest /= FO;
    int s = rest % NS; int b = rest / NS;
    float v = bias[d];
    long long ybase = ((long long)(b * NS + s)) * L;
#pragma unroll
    for (int tap = 0; tap < 8; ++tap) {
        int l = p + tap - 7;
        if (l >= 0 && l < L) v += Y[(ybase + l) * 512 + tap * 64 + d];
    }
    long long oi = swap ? (((long long)(b * 64 + d) * FO + p) * NS + s)
                        : (((long long)(b * 64 + d) * NS + s) * FO + p);
    out[oi] = v + resid[oi];
}

// ---------------- 3x3 stride2 pad1 conv + ReLU, LDS-tiled ----------------
__global__ __launch_bounds__(256) void down_tile_k(const float* __restrict__ in,
    const float* __restrict__ w, const float* __restrict__ bias,
    float* __restrict__ out, int Hi, int Wi)
{
    int Ho = Hi >> 1, Wo = Wi >> 1;
    int ntx = Wo >> 3, nty = Ho >> 3;
    int tx = blockIdx.x % ntx; int rest = blockIdx.x / ntx;
    int ty = rest % nty; int b = rest / nty;
    int y0 = ty * 8, x0 = tx * 8;
    __shared__ float Ws[64][9];
    __shared__ float Is[17][21];
    int tid = threadIdx.x;
    int tm = tid >> 4, tn = tid & 15;
    float acc[4][4];
#pragma unroll
    for (int i = 0; i < 4; ++i)
#pragma unroll
        for (int j = 0; j < 4; ++j) acc[i][j] = 0.f;

    const float* ib = in + (long long)b * 64 * Hi * Wi;
    for (int c = 0; c < 64; ++c) {
        for (int idx = tid; idx < 576; idx += 256) {
            int d = idx / 9, t = idx - d * 9;
            Ws[d][t] = w[((d << 6) + c) * 9 + t];
        }
        const float* icp = ib + (long long)c * Hi * Wi;
        for (int idx = tid; idx < 289; idx += 256) {
            int r = idx / 17, s = idx - r * 17;
            int iy = 2 * y0 - 1 + r, ix = 2 * x0 - 1 + s;
            float v = 0.f;
            if (iy >= 0 && iy < Hi && ix >= 0 && ix < Wi) v = icp[(long long)iy * Wi + ix];
            Is[r][s] = v;
        }
        __syncthreads();
        float wr[4][9];
#pragma unroll
        for (int dd = 0; dd < 4; ++dd)
#pragma unroll
            for (int t = 0; t < 9; ++t) wr[dd][t] = Ws[tm * 4 + dd][t];
#pragma unroll
        for (int pp = 0; pp < 4; ++pp) {
            int p = tn * 4 + pp; int py = p >> 3, px = p & 7;
            float iv[9];
#pragma unroll
            for (int kh = 0; kh < 3; ++kh)
#pragma unroll
                for (int kw = 0; kw < 3; ++kw)
                    iv[kh * 3 + kw] = Is[2 * py + kh][2 * px + kw];
#pragma unroll
            for (int dd = 0; dd < 4; ++dd)
#pragma unroll
                for (int t = 0; t < 9; ++t) acc[dd][pp] += wr[dd][t] * iv[t];
        }
        __syncthreads();
    }
#pragma unroll
    for (int dd = 0; dd < 4; ++dd) {
        int d = tm * 4 + dd;
        float bsv = bias[d];
#pragma unroll
        for (int pp = 0; pp < 4; ++pp) {
            int p = tn * 4 + pp; int py = p >> 3, px = p & 7;
            out[(((long long)b * 64 + d) * Ho + (y0 + py)) * Wo + (x0 + px)] =
                fmaxf(acc[dd][pp] + bsv, 0.f);
        }
    }
}

// ---------------- unfolds -> bf16 ----------------
__global__ void unfold_freq_k(const float* __restrict__ ag, ushort* __restrict__ u)
{
    long long gid = (long long)blockIdx.x * blockDim.x + threadIdx.x;
    if (gid >= (long long)MF * II) return;
    int ch = (int)(gid & 511); int row = (int)(gid >> 9);
    int b = row / (T4 * LF); int rem = row - b * (T4 * LF);
    int t = rem / LF; int l = rem - t * LF;
    int d = ch >> 3, i = ch & 7;
    u[gid] = f2b(ag[((long long)((b * DD + d) * T4 + t)) * F4 + l + i]);
}
__global__ void unfold_time_k(const float* __restrict__ ag, ushort* __restrict__ u)
{
    long long gid = (long long)blockIdx.x * blockDim.x + threadIdx.x;
    if (gid >= (long long)MT * II) return;
    int ch = (int)(gid & 511); int row = (int)(gid >> 9);
    int b = row / (F4 * LT); int rem = row - b * (F4 * LT);
    int tt = rem / LT; int l = rem - tt * LT;
    int d = ch >> 3, i = ch & 7;
    u[gid] = f2b(ag[((long long)((b * DD + d) * T4 + (l + i))) * F4 + tt]);
}

// ---------------- weight packing (transposed, bf16) ----------------
__global__ void pack_wcatT_k(const float* __restrict__ Wx, const float* __restrict__ Whw,
                             ushort* __restrict__ WT)
{
    int gid = blockIdx.x * blockDim.x + threadIdx.x;
    if (gid >= 1024 * 512) return;
    int k = gid & 511; int n = gid >> 9;
    int dir = n >> 9; int c = n & 511;
    float v = (c < 384) ? Wx[(dir * 512 + k) * 384 + c]
                        : Whw[(dir * 512 + k) * 128 + (c - 384)];
    WT[gid] = f2b(v);
}
__global__ void pack_pwT_k(const float* __restrict__ pw, ushort* __restrict__ WT)
{
    int gid = blockIdx.x * blockDim.x + threadIdx.x;
    if (gid >= 512 * 256) return;
    int k = gid & 255; int n = gid >> 8;
    WT[gid] = f2b(pw[k * 512 + n]);
}
__global__ void pack_wct2T_k(const float* __restrict__ ctw, ushort* __restrict__ WT)
{
    int gid = blockIdx.x * blockDim.x + threadIdx.x;
    if (gid >= 512 * 512) return;
    int k = gid & 511; int n = gid >> 9;
    int tap = n >> 6, d = n & 63;
    WT[gid] = f2b(ctw[((d * 512) + k) * 8 + tap]);
}

// ---------------- SRU elementwise recurrence (G f32 -> h bf16) ----------------
__global__ void sru_scan_k(const float* __restrict__ G, const float* __restrict__ bfw,
                           const float* __restrict__ brw, ushort* __restrict__ hout,
                           int Nn, int L)
{
    int gid = blockIdx.x * blockDim.x + threadIdx.x;
    if (gid >= Nn * 256) return;
    int h = gid & 127; int dir = (gid >> 7) & 1; int n = gid >> 8;
    const float bf = bfw[dir * 128 + h], br = brw[dir * 128 + h];
    int base = dir * 512 + h;
    float c = 0.f;
    for (int s = 0; s < L; ++s) {
        int l = dir ? (L - 1 - s) : s;
        const float* g = G + ((long long)(n * L + l)) * 1024 + base;
        float xt = g[0];
        float fv = 1.f / (1.f + __expf(-(g[128] + bf)));
        float rv = 1.f / (1.f + __expf(-(g[256] + br)));
        float xh = g[384];
        c = fv * c + (1.f - fv) * xt;
        float hv = rv * c + (1.f - rv) * xh;
        hout[((long long)(n * L + l)) * 256 + dir * 128 + h] = f2b(hv);
    }
}

// ---------------- host launch ----------------
extern "C" void kernel_launch(void* const* d_in, const int* in_sizes, int n_in,
                              void* d_out, int out_size, void* d_ws, size_t ws_size,
                              hipStream_t stream)
{
    const float* A_in  = (const float*)d_in[0];
    const float* cw    = (const float*)d_in[1];
    const float* cb    = (const float*)d_in[2];
    const float* dw0   = (const float*)d_in[3];
    const float* db0   = (const float*)d_in[4];
    const float* dw1   = (const float*)d_in[5];
    const float* db1   = (const float*)d_in[6];
    const float* f_Wx  = (const float*)d_in[7];
    const float* f_bf  = (const float*)d_in[8];
    const float* f_br  = (const float*)d_in[9];
    const float* f_Whw = (const float*)d_in[10];
    const float* f_pw  = (const float*)d_in[11];
    const float* f_pb  = (const float*)d_in[12];
    const float* f_ctw = (const float*)d_in[13];
    const float* f_ctb = (const float*)d_in[14];
    const float* t_Wx  = (const float*)d_in[15];
    const float* t_bf  = (const float*)d_in[16];
    const float* t_br  = (const float*)d_in[17];
    const float* t_Whw = (const float*)d_in[18];
    const float* t_pw  = (const float*)d_in[19];
    const float* t_pb  = (const float*)d_in[20];
    const float* t_ctw = (const float*)d_in[21];
    const float* t_ctb = (const float*)d_in[22];
    const float* qkv_w = (const float*)d_in[23];
    const float* qkv_b = (const float*)d_in[24];
    const float* ow    = (const float*)d_in[25];
    const float* ob    = (const float*)d_in[26];
    const float* upw0  = (const float*)d_in[27];
    const float* upb0  = (const float*)d_in[28];
    const float* upw1  = (const float*)d_in[29];
    const float* upb1  = (const float*)d_in[30];
    const float* fw    = (const float*)d_in[31];
    const float* fb    = (const float*)d_in[32];

    float* ws  = (float*)d_ws;
    float* out = (float*)d_out;

    // workspace layout (f32 units)
    float* ag    = ws + 0;          // 1,048,576
    float* x1    = ws + 1048576;    // 4,194,304
    float* Ureg  = ws + 5242880;    // 7,471,104 : u16 / Y / y1
    float* G     = ws + 12713984;   // 14,942,208 (later y0)
    float* h16f  = ws + 27656192;   // h bf16
    float* z16f  = ws + 29523968;   // z bf16
    float* wcatf = ws + 33259520;   // WcatT bf16
    float* wct2f = ws + 33521664;   // Wct2T bf16
    float* pwtf  = ws + 33652736;   // pwT bf16
    float* fout  = ws + 33718272;
    float* tout  = ws + 34766848;
    float* qkvbf = ws + 35815424;   // qkv bf16 (1,572,864 f32 slots)
    float* attnO = ws + 38961152;
    float* dp    = ws + 40009728;
    float* cw16f = ws + 41058304;   // cw bf16
    float* fw16f = ws + 41066496;   // fw bf16
    float* wup0f = ws + 41074688;   // up0 weights bf16 (8192)
    float* wup1f = ws + 41082880;   // up1 weights bf16 (8192)
    float* qkvwf = ws + 41091072;   // qkv_w^T bf16 (6144)
    float* owtf  = ws + 41097216;   // ow^T bf16 (2048)
    ushort* u16    = (ushort*)Ureg;
    float*  Y      = Ureg;
    float*  y1     = Ureg;
    float*  y0     = G;
    ushort* h16    = (ushort*)h16f;
    ushort* z16    = (ushort*)z16f;
    ushort* WcatT  = (ushort*)wcatf;
    ushort* Wct2T  = (ushort*)wct2f;
    ushort* pwT    = (ushort*)pwtf;
    ushort* qkv16  = (ushort*)qkvbf;
    ushort* cw16   = (ushort*)cw16f;
    ushort* fw16   = (ushort*)fw16f;
    ushort* WupT0  = (ushort*)wup0f;
    ushort* WupT1  = (ushort*)wup1f;
    ushort* qkvwT  = (ushort*)qkvwf;
    ushort* owT    = (ushort*)owtf;
    float*  x0     = out;           // x0 parked in d_out

    dim3 blk(256);

    // weight packs
    pack_w16_k<<<dim3(64), blk, 0, stream>>>(cw, cw16, 16384);
    pack_w16_k<<<dim3(64), blk, 0, stream>>>(fw, fw16, 16384);
    pack_upw_k<<<dim3(64), blk, 0, stream>>>(upw0, WupT0);
    pack_upw_k<<<dim3(64), blk, 0, stream>>>(upw1, WupT1);
    pack_transposeT_k<<<dim3(48), blk, 0, stream>>>(qkv_w, qkvwT, 64, 192);
    pack_transposeT_k<<<dim3(16), blk, 0, stream>>>(ow, owT, 64, 64);

    // 1. compress (bf16 MFMA implicit GEMM over NCHW)
    mfma_nchw_k<64><<<dim3(256, 1, 8), blk, 0, stream>>>(A_in, cw16, cb, x0, 32768, 64, 256);

    // 2-3. downsample
    down_tile_k<<<dim3(1024), blk, 0, stream>>>(x0, dw0, db0, x1, TT, FF);
    down_tile_k<<<dim3(256), blk, 0, stream>>>(x1, dw1, db1, ag, T2, F2);

    // ---- frequency pathway ----
    unfold_freq_k<<<dim3((MF * II) / 256), blk, 0, stream>>>(ag, u16);
    pack_wcatT_k<<<dim3(2048), blk, 0, stream>>>(f_Wx, f_Whw, WcatT);
    mfma_gemm_k<<<dim3(8, MF / 128), blk, 0, stream>>>(u16, WcatT, G, nullptr, nullptr,
        MF, 1024, 512, 0);
    sru_scan_k<<<dim3(131072 / 256), blk, 0, stream>>>(G, f_bf, f_br, h16, 512, LF);
    pack_pwT_k<<<dim3(512), blk, 0, stream>>>(f_pw, pwT);
    mfma_gemm_k<<<dim3(4, MF / 128), blk, 0, stream>>>(h16, pwT, nullptr, z16, f_pb,
        MF, 512, 256, 1);
    pack_wct2T_k<<<dim3(1024), blk, 0, stream>>>(f_ctw, Wct2T);
    mfma_gemm_k<<<dim3(4, MF / 128), blk, 0, stream>>>(z16, Wct2T, Y, nullptr, nullptr,
        MF, 512, 512, 0);
    convt_reduce_k<<<dim3(4096), blk, 0, stream>>>(Y, f_ctb, ag, fout, 64, LF, 32, 0);

    // ---- time pathway ----
    unfold_time_k<<<dim3((MT * II) / 256), blk, 0, stream>>>(ag, u16);
    pack_wcatT_k<<<dim3(2048), blk, 0, stream>>>(t_Wx, t_Whw, WcatT);
    mfma_gemm_k<<<dim3(8, MT / 128), blk, 0, stream>>>(u16, WcatT, G, nullptr, nullptr,
        MT, 1024, 512, 0);
    sru_scan_k<<<dim3(65536 / 256), blk, 0, stream>>>(G, t_bf, t_br, h16, 256, LT);
    pack_pwT_k<<<dim3(512), blk, 0, stream>>>(t_pw, pwT);
    mfma_gemm_k<<<dim3(4, MT / 128), blk, 0, stream>>>(h16, pwT, nullptr, z16, t_pb,
        MT, 512, 256, 1);
    pack_wct2T_k<<<dim3(1024), blk, 0, stream>>>(t_ctw, Wct2T);
    mfma_gemm_k<<<dim3(4, MT / 128), blk, 0, stream>>>(z16, Wct2T, Y, nullptr, nullptr,
        MT, 512, 512, 0);
    convt_reduce_k<<<dim3(4096), blk, 0, stream>>>(Y, t_ctb, fout, tout, 32, LT, 64, 1);

    // ---- attention ----
    mfma_qkv_k<<<dim3(16, 1, 8), blk, 0, stream>>>(tout, qkvwT, qkv_b, qkv16);
    attn_mfma_k<<<dim3(16, NHEADS, BB), blk, 0, stream>>>(qkv16, attnO);
    mfma_attnout_k<<<dim3(16, 1, 8), blk, 0, stream>>>(attnO, owT, ob, tout, dp);

    // ---- reconstruction (MFMA up-convs, fused bias+residual) ----
    up_mfma_k<<<dim3(16, 2, 8), blk, 0, stream>>>(dp, WupT0, upb0, x1, y1, 2048, 5);
    up_mfma_k<<<dim3(64, 2, 8), blk, 0, stream>>>(y1, WupT1, upb1, x0, y0, 8192, 6);

    // final 1x1 conv (bf16 MFMA implicit GEMM)
    mfma_nchw_k<128><<<dim3(256, 2, 8), blk, 0, stream>>>(y0, fw16, fb, out, 32768, 256, 64);
}

// Round 6
// 709.735 us; speedup vs baseline: 5.8393x; 1.2346x over previous
//
#include <hip/hip_runtime.h>

// ---------------- problem constants ----------------
#define BB 8
#define CC 256
#define TT 256
#define FF 128
#define DD 64
#define HH 128
#define NHEADS 4
#define KK 8
#define II 512            // D*K
#define T2 128
#define F2 64
#define T4 64
#define F4 32
#define P4 2048           // T4*F4

// freq pathway: N=512 seqs, L=25 ; time pathway: N=256 seqs, L=57
#define LF 25
#define LT 57
#define MF (512*LF)       // 12800
#define MT (256*LT)       // 14592

typedef __attribute__((ext_vector_type(8))) short bf16x8;
typedef __attribute__((ext_vector_type(4))) float f32x4;

__device__ __forceinline__ ushort f2b(float x) {
    unsigned u = __float_as_uint(x);
    unsigned r = (u + 0x7FFFu + ((u >> 16) & 1u)) >> 16;
    return (ushort)r;
}
__device__ __forceinline__ float b2f(ushort x) {
    return __uint_as_float(((unsigned)x) << 16);
}
__device__ __forceinline__ unsigned cvtpk_bf16(float lo, float hi) {
    unsigned r;
    asm("v_cvt_pk_bf16_f32 %0, %1, %2" : "=v"(r) : "v"(lo), "v"(hi));
    return r;
}

// ---------------- bf16 MFMA GEMM: C(MxN) = A16(MxK) * BT16(NxK)^T ----------------
__global__ __launch_bounds__(256) void mfma_gemm_k(
    const ushort* __restrict__ A16, const ushort* __restrict__ BT16,
    float* __restrict__ C, ushort* __restrict__ C16,
    const float* __restrict__ bias,
    int M, int N, int K, int out16)
{
    __shared__ ushort As[128][40];
    __shared__ ushort Bs[128][40];
    int m0 = blockIdx.y * 128, n0 = blockIdx.x * 128;
    int tid = threadIdx.x;
    int wave = tid >> 6, lane = tid & 63;
    int wm = (wave & 1) * 64, wn = (wave >> 1) * 64;
    int l15 = lane & 15, lhi = lane >> 4;
    f32x4 acc[4][4] = {};
    int rs = tid >> 2, qs = tid & 3;

    for (int k0 = 0; k0 < K; k0 += 32) {
        *(uint4*)&As[rs][qs * 8]      = *(const uint4*)(A16 + (long long)(m0 + rs) * K + k0 + qs * 8);
        *(uint4*)&As[rs + 64][qs * 8] = *(const uint4*)(A16 + (long long)(m0 + rs + 64) * K + k0 + qs * 8);
        *(uint4*)&Bs[rs][qs * 8]      = *(const uint4*)(BT16 + (long long)(n0 + rs) * K + k0 + qs * 8);
        *(uint4*)&Bs[rs + 64][qs * 8] = *(const uint4*)(BT16 + (long long)(n0 + rs + 64) * K + k0 + qs * 8);
        __syncthreads();
        bf16x8 af[4], bfr[4];
#pragma unroll
        for (int fr = 0; fr < 4; ++fr)
            af[fr] = *(const bf16x8*)&As[wm + fr * 16 + l15][lhi * 8];
#pragma unroll
        for (int fc = 0; fc < 4; ++fc)
            bfr[fc] = *(const bf16x8*)&Bs[wn + fc * 16 + l15][lhi * 8];
#pragma unroll
        for (int fr = 0; fr < 4; ++fr)
#pragma unroll
            for (int fc = 0; fc < 4; ++fc)
                acc[fr][fc] = __builtin_amdgcn_mfma_f32_16x16x32_bf16(af[fr], bfr[fc], acc[fr][fc], 0, 0, 0);
        __syncthreads();
    }
#pragma unroll
    for (int fr = 0; fr < 4; ++fr) {
#pragma unroll
        for (int fc = 0; fc < 4; ++fc) {
            int col = n0 + wn + fc * 16 + l15;
            float bv = bias ? bias[col] : 0.f;
#pragma unroll
            for (int r = 0; r < 4; ++r) {
                int row = m0 + wm + fr * 16 + lhi * 4 + r;
                float v = acc[fr][fc][r] + bv;
                long long ci = (long long)row * N + col;
                if (out16) C16[ci] = f2b(v);
                else       C[ci] = v;
            }
        }
    }
}

// ---------------- bf16 MFMA implicit GEMM over NCHW f32 activations ----------------
template<int BN>
__global__ __launch_bounds__(256) void mfma_nchw_k(
    const float* __restrict__ X, const ushort* __restrict__ WT,
    const float* __restrict__ bias, float* __restrict__ Y,
    int P, int N, int K)
{
    constexpr int FC = BN / 32;
    __shared__ ushort As[128][40];
    int p0 = blockIdx.x * 128;
    int n0 = blockIdx.y * BN;
    int b  = blockIdx.z;
    int tid = threadIdx.x, wave = tid >> 6, lane = tid & 63;
    int l15 = lane & 15, lhi = lane >> 4;
    int wm = (wave & 1) * 64, wn = (wave >> 1) * (BN / 2);
    f32x4 acc[4][FC] = {};
    const float* Xb = X + (long long)b * K * P;
    int kk_s = tid >> 3, pq_s = tid & 7;

    for (int k0 = 0; k0 < K; k0 += 32) {
        const float* xr = Xb + (long long)(k0 + kk_s) * P + p0;
#pragma unroll
        for (int j = 0; j < 4; ++j) {
            float4 v = *(const float4*)(xr + j * 32 + pq_s * 4);
            int pp = j * 32 + pq_s * 4;
            As[pp][kk_s]     = f2b(v.x);
            As[pp + 1][kk_s] = f2b(v.y);
            As[pp + 2][kk_s] = f2b(v.z);
            As[pp + 3][kk_s] = f2b(v.w);
        }
        __syncthreads();
        bf16x8 af[4], bfr[FC];
#pragma unroll
        for (int fr = 0; fr < 4; ++fr)
            af[fr] = *(const bf16x8*)&As[wm + fr * 16 + l15][lhi * 8];
#pragma unroll
        for (int fc = 0; fc < FC; ++fc)
            bfr[fc] = *(const bf16x8*)(WT + (long long)(n0 + wn + fc * 16 + l15) * K + k0 + lhi * 8);
#pragma unroll
        for (int fr = 0; fr < 4; ++fr)
#pragma unroll
            for (int fc = 0; fc < FC; ++fc)
                acc[fr][fc] = __builtin_amdgcn_mfma_f32_16x16x32_bf16(af[fr], bfr[fc], acc[fr][fc], 0, 0, 0);
        __syncthreads();
    }
#pragma unroll
    for (int fc = 0; fc < FC; ++fc) {
        int n = n0 + wn + fc * 16 + l15;
        float bv = bias[n];
        float* yr = Y + ((long long)(b * N + n)) * P + p0 + wm + lhi * 4;
#pragma unroll
        for (int fr = 0; fr < 4; ++fr) {
            float4 o;
            o.x = acc[fr][fc][0] + bv;
            o.y = acc[fr][fc][1] + bv;
            o.z = acc[fr][fc][2] + bv;
            o.w = acc[fr][fc][3] + bv;
            *(float4*)(yr + fr * 16) = o;
        }
    }
}

// ---------------- 3x3 s2 p1 conv + ReLU as implicit bf16 MFMA GEMM ----------------
// block: (b, 8x8 output tile) x 64 out-channels = 64x64 GEMM tile, K = 64c x 9taps.
// LDS: 17x17x64 bf16 halo patch, XOR-swizzled (G4) to kill the 128B-stride conflict.
__global__ __launch_bounds__(256) void down_mfma_k(
    const float* __restrict__ in, const ushort* __restrict__ WT9,
    const float* __restrict__ bias, float* __restrict__ out,
    int Hi, int Wi)
{
    __shared__ ushort Is[289][64];
    int Ho = Hi >> 1, Wo = Wi >> 1;
    int ntx = Wo >> 3, nty = Ho >> 3;
    int tx = blockIdx.x % ntx; int rest = blockIdx.x / ntx;
    int ty = rest % nty; int b = rest / nty;
    int oy0 = ty * 8, ox0 = tx * 8;
    int iy0 = oy0 * 2 - 1, ix0 = ox0 * 2 - 1;
    int tid = threadIdx.x, wave = tid >> 6, lane = tid & 63;
    int l15 = lane & 15, lhi = lane >> 4;
    int wm = (wave & 1) * 32, wn = (wave >> 1) * 32;

    const float* ib = in + (long long)b * 64 * Hi * Wi;
    for (int i = tid; i < 289 * 64; i += 256) {
        int c = i / 289; int sp = i - c * 289;
        int r = sp / 17; int s = sp - r * 17;
        int iy = iy0 + r, ix = ix0 + s;
        float v = 0.f;
        if (iy >= 0 && iy < Hi && ix >= 0 && ix < Wi)
            v = ib[(long long)c * Hi * Wi + (long long)iy * Wi + ix];
        Is[sp][c ^ ((sp & 7) << 3)] = f2b(v);
    }
    __syncthreads();

    f32x4 acc[2][2] = {};
#pragma unroll
    for (int tap = 0; tap < 9; ++tap) {
        int kh = tap / 3, kw = tap - kh * 3;
#pragma unroll
        for (int half = 0; half < 2; ++half) {
            int c0 = half * 32 + lhi * 8;
            bf16x8 af[2], bw[2];
#pragma unroll
            for (int fr = 0; fr < 2; ++fr) {
                int p = wm + fr * 16 + l15;
                int sp = (2 * (p >> 3) + kh) * 17 + 2 * (p & 7) + kw;
                af[fr] = *(const bf16x8*)&Is[sp][c0 ^ ((sp & 7) << 3)];
            }
#pragma unroll
            for (int fc = 0; fc < 2; ++fc) {
                int d = wn + fc * 16 + l15;
                bw[fc] = *(const bf16x8*)(WT9 + (tap * 64 + d) * 64 + c0);
            }
#pragma unroll
            for (int fr = 0; fr < 2; ++fr)
#pragma unroll
                for (int fc = 0; fc < 2; ++fc)
                    acc[fr][fc] = __builtin_amdgcn_mfma_f32_16x16x32_bf16(af[fr], bw[fc], acc[fr][fc], 0, 0, 0);
        }
    }
#pragma unroll
    for (int fc = 0; fc < 2; ++fc) {
        int d = wn + fc * 16 + l15;
        float bv = bias[d];
        long long obase = ((long long)(b * 64 + d)) * Ho * Wo;
#pragma unroll
        for (int fr = 0; fr < 2; ++fr) {
#pragma unroll
            for (int r = 0; r < 4; ++r) {
                int p = wm + fr * 16 + lhi * 4 + r;
                int py = p >> 3, px = p & 7;
                out[obase + (long long)(oy0 + py) * Wo + ox0 + px] =
                    fmaxf(acc[fr][fc][r] + bv, 0.f);
            }
        }
    }
}

// WT9[(tap*64 + d)*64 + c] = w[d][c][kh][kw], tap = kh*3+kw
__global__ void pack_dw9_k(const float* __restrict__ w, ushort* __restrict__ O)
{
    int gid = blockIdx.x * blockDim.x + threadIdx.x;
    if (gid >= 9 * 64 * 64) return;
    int c = gid & 63; int rest = gid >> 6;
    int d = rest & 63; int tap = rest >> 6;
    O[gid] = f2b(w[(d * 64 + c) * 9 + tap]);
}

// ---------------- convT k=2 s=2 as MFMA ----------------
__global__ __launch_bounds__(256) void up_mfma_k(
    const float* __restrict__ in, const ushort* __restrict__ WT,
    const float* __restrict__ bias, const float* __restrict__ resid,
    float* __restrict__ out, int P, int wsh /*log2 Wi*/)
{
    __shared__ ushort As[128][72];
    int p0 = blockIdx.x * 128;
    int n0 = blockIdx.y * 128;
    int b  = blockIdx.z;
    int tid = threadIdx.x, wave = tid >> 6, lane = tid & 63;
    int l15 = lane & 15, lhi = lane >> 4;
    int wm = (wave & 1) * 64, wn = (wave >> 1) * 64;
    int Wi = 1 << wsh;
    int Ho = ((P >> wsh) << 1), Wo = Wi << 1;

    int kk_s = tid >> 3, pq_s = tid & 7;
#pragma unroll
    for (int h = 0; h < 2; ++h) {
        int k = h * 32 + kk_s;
        const float* xr = in + ((long long)(b * 64 + k)) * P + p0 + pq_s * 16;
#pragma unroll
        for (int j = 0; j < 4; ++j) {
            float4 v = *(const float4*)(xr + j * 4);
            int pp = pq_s * 16 + j * 4;
            As[pp][k]     = f2b(v.x);
            As[pp + 1][k] = f2b(v.y);
            As[pp + 2][k] = f2b(v.z);
            As[pp + 3][k] = f2b(v.w);
        }
    }
    __syncthreads();

    f32x4 acc[4][4] = {};
#pragma unroll
    for (int c = 0; c < 2; ++c) {
        bf16x8 af[4], bfr[4];
#pragma unroll
        for (int fr = 0; fr < 4; ++fr)
            af[fr] = *(const bf16x8*)&As[wm + fr * 16 + l15][c * 32 + lhi * 8];
#pragma unroll
        for (int fc = 0; fc < 4; ++fc)
            bfr[fc] = *(const bf16x8*)(WT + (long long)(n0 + wn + fc * 16 + l15) * 64 + c * 32 + lhi * 8);
#pragma unroll
        for (int fr = 0; fr < 4; ++fr)
#pragma unroll
            for (int fc = 0; fc < 4; ++fc)
                acc[fr][fc] = __builtin_amdgcn_mfma_f32_16x16x32_bf16(af[fr], bfr[fc], acc[fr][fc], 0, 0, 0);
    }

#pragma unroll
    for (int fc = 0; fc < 4; ++fc) {
        int n = n0 + wn + fc * 16 + l15;
        int parity = n >> 6, d = n & 63;
        int py = parity >> 1, px = parity & 1;
        float bv = bias[d];
        const long long obase = ((long long)(b * 64 + d)) * Ho * Wo;
#pragma unroll
        for (int fr = 0; fr < 4; ++fr) {
#pragma unroll
            for (int r = 0; r < 4; ++r) {
                int p = p0 + wm + fr * 16 + lhi * 4 + r;
                int iy = p >> wsh, ix = p & (Wi - 1);
                long long oi = obase + (long long)(2 * iy + py) * Wo + 2 * ix + px;
                out[oi] = acc[fr][fc][r] + bv + resid[oi];
            }
        }
    }
}

// ---------------- qkv projection: bf16 MFMA over NCHW tout -> bf16 [b][p][192] ----------------
__global__ __launch_bounds__(256) void mfma_qkv_k(
    const float* __restrict__ X, const ushort* __restrict__ WT,
    const float* __restrict__ bias, ushort* __restrict__ C16)
{
    __shared__ ushort As[128][72];
    int p0 = blockIdx.x * 128;
    int b  = blockIdx.z;
    int tid = threadIdx.x, wave = tid >> 6, lane = tid & 63;
    int l15 = lane & 15, lhi = lane >> 4;
    int wm = (wave & 1) * 64, wn = (wave >> 1) * 96;

    int kk_s = tid >> 3, pq_s = tid & 7;
#pragma unroll
    for (int h = 0; h < 2; ++h) {
        int k = h * 32 + kk_s;
        const float* xr = X + ((long long)(b * 64 + k)) * P4 + p0 + pq_s * 16;
#pragma unroll
        for (int j = 0; j < 4; ++j) {
            float4 v = *(const float4*)(xr + j * 4);
            int pp = pq_s * 16 + j * 4;
            As[pp][k]     = f2b(v.x);
            As[pp + 1][k] = f2b(v.y);
            As[pp + 2][k] = f2b(v.z);
            As[pp + 3][k] = f2b(v.w);
        }
    }
    __syncthreads();

    f32x4 acc[4][6] = {};
#pragma unroll
    for (int c = 0; c < 2; ++c) {
        bf16x8 af[4], bfr[6];
#pragma unroll
        for (int fr = 0; fr < 4; ++fr)
            af[fr] = *(const bf16x8*)&As[wm + fr * 16 + l15][c * 32 + lhi * 8];
#pragma unroll
        for (int fc = 0; fc < 6; ++fc)
            bfr[fc] = *(const bf16x8*)(WT + (long long)(wn + fc * 16 + l15) * 64 + c * 32 + lhi * 8);
#pragma unroll
        for (int fr = 0; fr < 4; ++fr)
#pragma unroll
            for (int fc = 0; fc < 6; ++fc)
                acc[fr][fc] = __builtin_amdgcn_mfma_f32_16x16x32_bf16(af[fr], bfr[fc], acc[fr][fc], 0, 0, 0);
    }
#pragma unroll
    for (int fc = 0; fc < 6; ++fc) {
        int n = wn + fc * 16 + l15;
        float bv = bias[n];
#pragma unroll
        for (int fr = 0; fr < 4; ++fr)
#pragma unroll
            for (int r = 0; r < 4; ++r) {
                int p = p0 + wm + fr * 16 + lhi * 4 + r;
                C16[((long long)(b * P4 + p)) * 192 + n] = f2b(acc[fr][fc][r] + bv);
            }
    }
}

// ---------------- attention out-proj ----------------
__global__ __launch_bounds__(256) void mfma_attnout_k(
    const float* __restrict__ A, const ushort* __restrict__ owT,
    const float* __restrict__ ob, const float* __restrict__ resid,
    float* __restrict__ dp)
{
    __shared__ ushort As[128][72];
    int p0 = blockIdx.x * 128;
    int b  = blockIdx.z;
    int tid = threadIdx.x, wave = tid >> 6, lane = tid & 63;
    int l15 = lane & 15, lhi = lane >> 4;
    int wm = (wave & 1) * 64, wn = (wave >> 1) * 32;

    int rs = tid >> 2, qs = tid & 3;
#pragma unroll
    for (int h = 0; h < 2; ++h) {
        int row = h * 64 + rs;
        const float* ar = A + ((long long)(b * P4 + p0 + row)) * 64 + qs * 16;
#pragma unroll
        for (int j = 0; j < 4; ++j) {
            float4 v = *(const float4*)(ar + j * 4);
            int c = qs * 16 + j * 4;
            *(unsigned*)&As[row][c]     = cvtpk_bf16(v.x, v.y);
            *(unsigned*)&As[row][c + 2] = cvtpk_bf16(v.z, v.w);
        }
    }
    __syncthreads();

    f32x4 acc[4][2] = {};
#pragma unroll
    for (int c = 0; c < 2; ++c) {
        bf16x8 af[4], bfr[2];
#pragma unroll
        for (int fr = 0; fr < 4; ++fr)
            af[fr] = *(const bf16x8*)&As[wm + fr * 16 + l15][c * 32 + lhi * 8];
#pragma unroll
        for (int fc = 0; fc < 2; ++fc)
            bfr[fc] = *(const bf16x8*)(owT + (long long)(wn + fc * 16 + l15) * 64 + c * 32 + lhi * 8);
#pragma unroll
        for (int fr = 0; fr < 4; ++fr)
#pragma unroll
            for (int fc = 0; fc < 2; ++fc)
                acc[fr][fc] = __builtin_amdgcn_mfma_f32_16x16x32_bf16(af[fr], bfr[fc], acc[fr][fc], 0, 0, 0);
    }
#pragma unroll
    for (int fc = 0; fc < 2; ++fc) {
        int n = wn + fc * 16 + l15;
        float bv = ob[n];
        long long base = ((long long)(b * 64 + n)) * P4;
#pragma unroll
        for (int fr = 0; fr < 4; ++fr) {
            int p = p0 + wm + fr * 16 + lhi * 4;
            float4 rv = *(const float4*)(resid + base + p);
            float4 o;
            o.x = acc[fr][fc][0] + bv + rv.x;
            o.y = acc[fr][fc][1] + bv + rv.y;
            o.z = acc[fr][fc][2] + bv + rv.z;
            o.w = acc[fr][fc][3] + bv + rv.w;
            *(float4*)(dp + base + p) = o;
        }
    }
}

__global__ void pack_w16_k(const float* __restrict__ W, ushort* __restrict__ O, int n)
{
    int gid = blockIdx.x * blockDim.x + threadIdx.x;
    if (gid < n) O[gid] = f2b(W[gid]);
}
__global__ void pack_transposeT_k(const float* __restrict__ W, ushort* __restrict__ O,
                                  int K, int N)
{
    int gid = blockIdx.x * blockDim.x + threadIdx.x;
    if (gid >= K * N) return;
    int k = gid % K, n = gid / K;
    O[gid] = f2b(W[(long long)k * N + n]);
}
__global__ void pack_upw_k(const float* __restrict__ w, ushort* __restrict__ O)
{
    int gid = blockIdx.x * blockDim.x + threadIdx.x;
    if (gid >= 16384) return;
    int c = gid & 63; int n = gid >> 6;
    int parity = n >> 6, d = n & 63;
    int py = parity >> 1, px = parity & 1;
    O[gid] = f2b(w[((d * 64 + c) * 2 + (1 - py)) * 2 + (1 - px)]);
}

// ---------------- MFMA flash attention (dh=16, 4 heads), bf16 qkv input ----------------
__global__ __launch_bounds__(256) void attn_mfma_k(const ushort* __restrict__ qkv,
                                                   float* __restrict__ out)
{
    __shared__ ushort Qs[128][40];
    __shared__ ushort Ks[64][40];
    __shared__ ushort VsT[16][72];
    __shared__ ushort Ps[128][72];
    int qt = blockIdx.x, h = blockIdx.y, b = blockIdx.z;
    int tid = threadIdx.x, wave = tid >> 6, lane = tid & 63;
    int l15 = lane & 15, lhi = lane >> 4;
    int q0 = wave * 32;

    for (int i = tid; i < 1024; i += 256) {
        int row = i >> 3, c = i & 7;
        *(unsigned*)&Qs[row][16 + c * 2] = 0u;
    }
    for (int i = tid; i < 512; i += 256) {
        int row = i >> 3, c = i & 7;
        *(unsigned*)&Ks[row][16 + c * 2] = 0u;
    }
    {
        const ushort* qp = qkv + ((long long)(b * P4 + qt * 128)) * 192 + h * 16;
        for (int i = tid; i < 2048; i += 256) {
            int row = i >> 4, d = i & 15;
            Qs[row][d] = f2b(b2f(qp[row * 192 + d]) * 0.25f);
        }
    }
    __syncthreads();

    float mmax[2] = {-1e30f, -1e30f};
    float lsum[2] = {0.f, 0.f};
    f32x4 oacc[2] = {};

    for (int k0 = 0; k0 < P4; k0 += 64) {
        const ushort* kp = qkv + ((long long)(b * P4 + k0)) * 192 + 64 + h * 16;
        for (int i = tid; i < 1024; i += 256) {
            int key = i >> 4, d = i & 15;
            Ks[key][d]  = kp[key * 192 + d];
            VsT[d][key] = kp[key * 192 + 64 + d];
        }
        __syncthreads();

        bf16x8 bq[2];
        bq[0] = *(const bf16x8*)&Qs[q0 + l15][lhi * 8];
        bq[1] = *(const bf16x8*)&Qs[q0 + 16 + l15][lhi * 8];
        f32x4 s[4][2];
#pragma unroll
        for (int fr = 0; fr < 4; ++fr) {
            bf16x8 ak = *(const bf16x8*)&Ks[fr * 16 + l15][lhi * 8];
            f32x4 z = {};
            s[fr][0] = __builtin_amdgcn_mfma_f32_16x16x32_bf16(ak, bq[0], z, 0, 0, 0);
            s[fr][1] = __builtin_amdgcn_mfma_f32_16x16x32_bf16(ak, bq[1], z, 0, 0, 0);
        }
#pragma unroll
        for (int fc = 0; fc < 2; ++fc) {
            float m = s[0][fc][0];
#pragma unroll
            for (int fr = 0; fr < 4; ++fr)
#pragma unroll
                for (int r = 0; r < 4; ++r) m = fmaxf(m, s[fr][fc][r]);
            m = fmaxf(m, __shfl_xor(m, 16));
            m = fmaxf(m, __shfl_xor(m, 32));
            float nm = fmaxf(mmax[fc], m);
            float corr = __expf(mmax[fc] - nm);
            mmax[fc] = nm;
            float ps = 0.f;
#pragma unroll
            for (int fr = 0; fr < 4; ++fr)
#pragma unroll
                for (int r = 0; r < 4; ++r) {
                    float p = __expf(s[fr][fc][r] - nm);
                    s[fr][fc][r] = p;
                    ps += p;
                }
            lsum[fc] = lsum[fc] * corr + ps;
#pragma unroll
            for (int r = 0; r < 4; ++r) oacc[fc][r] *= corr;
        }
#pragma unroll
        for (int fc = 0; fc < 2; ++fc)
#pragma unroll
            for (int fr = 0; fr < 4; ++fr) {
                uint2 pk;
                pk.x = cvtpk_bf16(s[fr][fc][0], s[fr][fc][1]);
                pk.y = cvtpk_bf16(s[fr][fc][2], s[fr][fc][3]);
                *(uint2*)&Ps[q0 + fc * 16 + l15][fr * 16 + lhi * 4] = pk;
            }
#pragma unroll
        for (int ks = 0; ks < 2; ++ks) {
            bf16x8 av = *(const bf16x8*)&VsT[l15][ks * 32 + lhi * 8];
#pragma unroll
            for (int fc = 0; fc < 2; ++fc) {
                bf16x8 bp = *(const bf16x8*)&Ps[q0 + fc * 16 + l15][ks * 32 + lhi * 8];
                oacc[fc] = __builtin_amdgcn_mfma_f32_16x16x32_bf16(av, bp, oacc[fc], 0, 0, 0);
            }
        }
        __syncthreads();
    }
#pragma unroll
    for (int fc = 0; fc < 2; ++fc) {
        float L = lsum[fc];
        L += __shfl_xor(L, 16);
        L += __shfl_xor(L, 32);
        float inv = 1.f / L;
        int q = qt * 128 + q0 + fc * 16 + l15;
        float* op = out + ((long long)(b * P4 + q)) * 64 + h * 16 + lhi * 4;
#pragma unroll
        for (int r = 0; r < 4; ++r) op[r] = oacc[fc][r] * inv;
    }
}

// ---------------- convT(1,8) tap-reduce ----------------
__global__ void convt_reduce_k(const float* __restrict__ Y, const float* __restrict__ bias,
                               const float* __restrict__ resid, float* __restrict__ out,
                               int NS, int L, int FO, int swap)
{
    int gid = blockIdx.x * blockDim.x + threadIdx.x;
    int total = BB * 64 * NS * FO;
    if (gid >= total) return;
    int d = gid & 63; int rest = gid >> 6;
    int p = rest % FO; rest /= FO;
    int s = rest % NS; int b = rest / NS;
    float v = bias[d];
    long long ybase = ((long long)(b * NS + s)) * L;
#pragma unroll
    for (int tap = 0; tap < 8; ++tap) {
        int l = p + tap - 7;
        if (l >= 0 && l < L) v += Y[(ybase + l) * 512 + tap * 64 + d];
    }
    long long oi = swap ? (((long long)(b * 64 + d) * FO + p) * NS + s)
                        : (((long long)(b * 64 + d) * NS + s) * FO + p);
    out[oi] = v + resid[oi];
}

// ---------------- unfolds -> bf16 ----------------
__global__ void unfold_freq_k(const float* __restrict__ ag, ushort* __restrict__ u)
{
    long long gid = (long long)blockIdx.x * blockDim.x + threadIdx.x;
    if (gid >= (long long)MF * II) return;
    int ch = (int)(gid & 511); int row = (int)(gid >> 9);
    int b = row / (T4 * LF); int rem = row - b * (T4 * LF);
    int t = rem / LF; int l = rem - t * LF;
    int d = ch >> 3, i = ch & 7;
    u[gid] = f2b(ag[((long long)((b * DD + d) * T4 + t)) * F4 + l + i]);
}
__global__ void unfold_time_k(const float* __restrict__ ag, ushort* __restrict__ u)
{
    long long gid = (long long)blockIdx.x * blockDim.x + threadIdx.x;
    if (gid >= (long long)MT * II) return;
    int ch = (int)(gid & 511); int row = (int)(gid >> 9);
    int b = row / (F4 * LT); int rem = row - b * (F4 * LT);
    int tt = rem / LT; int l = rem - tt * LT;
    int d = ch >> 3, i = ch & 7;
    u[gid] = f2b(ag[((long long)((b * DD + d) * T4 + (l + i))) * F4 + tt]);
}

// ---------------- weight packing (transposed, bf16) ----------------
__global__ void pack_wcatT_k(const float* __restrict__ Wx, const float* __restrict__ Whw,
                             ushort* __restrict__ WT)
{
    int gid = blockIdx.x * blockDim.x + threadIdx.x;
    if (gid >= 1024 * 512) return;
    int k = gid & 511; int n = gid >> 9;
    int dir = n >> 9; int c = n & 511;
    float v = (c < 384) ? Wx[(dir * 512 + k) * 384 + c]
                        : Whw[(dir * 512 + k) * 128 + (c - 384)];
    WT[gid] = f2b(v);
}
__global__ void pack_pwT_k(const float* __restrict__ pw, ushort* __restrict__ WT)
{
    int gid = blockIdx.x * blockDim.x + threadIdx.x;
    if (gid >= 512 * 256) return;
    int k = gid & 255; int n = gid >> 8;
    WT[gid] = f2b(pw[k * 512 + n]);
}
__global__ void pack_wct2T_k(const float* __restrict__ ctw, ushort* __restrict__ WT)
{
    int gid = blockIdx.x * blockDim.x + threadIdx.x;
    if (gid >= 512 * 512) return;
    int k = gid & 511; int n = gid >> 9;
    int tap = n >> 6, d = n & 63;
    WT[gid] = f2b(ctw[((d * 512) + k) * 8 + tap]);
}

// ---------------- SRU elementwise recurrence (G f32 -> h bf16) ----------------
__global__ void sru_scan_k(const float* __restrict__ G, const float* __restrict__ bfw,
                           const float* __restrict__ brw, ushort* __restrict__ hout,
                           int Nn, int L)
{
    int gid = blockIdx.x * blockDim.x + threadIdx.x;
    if (gid >= Nn * 256) return;
    int h = gid & 127; int dir = (gid >> 7) & 1; int n = gid >> 8;
    const float bf = bfw[dir * 128 + h], br = brw[dir * 128 + h];
    int base = dir * 512 + h;
    float c = 0.f;
    for (int s = 0; s < L; ++s) {
        int l = dir ? (L - 1 - s) : s;
        const float* g = G + ((long long)(n * L + l)) * 1024 + base;
        float xt = g[0];
        float fv = 1.f / (1.f + __expf(-(g[128] + bf)));
        float rv = 1.f / (1.f + __expf(-(g[256] + br)));
        float xh = g[384];
        c = fv * c + (1.f - fv) * xt;
        float hv = rv * c + (1.f - rv) * xh;
        hout[((long long)(n * L + l)) * 256 + dir * 128 + h] = f2b(hv);
    }
}

// ---------------- host launch ----------------
extern "C" void kernel_launch(void* const* d_in, const int* in_sizes, int n_in,
                              void* d_out, int out_size, void* d_ws, size_t ws_size,
                              hipStream_t stream)
{
    const float* A_in  = (const float*)d_in[0];
    const float* cw    = (const float*)d_in[1];
    const float* cb    = (const float*)d_in[2];
    const float* dw0   = (const float*)d_in[3];
    const float* db0   = (const float*)d_in[4];
    const float* dw1   = (const float*)d_in[5];
    const float* db1   = (const float*)d_in[6];
    const float* f_Wx  = (const float*)d_in[7];
    const float* f_bf  = (const float*)d_in[8];
    const float* f_br  = (const float*)d_in[9];
    const float* f_Whw = (const float*)d_in[10];
    const float* f_pw  = (const float*)d_in[11];
    const float* f_pb  = (const float*)d_in[12];
    const float* f_ctw = (const float*)d_in[13];
    const float* f_ctb = (const float*)d_in[14];
    const float* t_Wx  = (const float*)d_in[15];
    const float* t_bf  = (const float*)d_in[16];
    const float* t_br  = (const float*)d_in[17];
    const float* t_Whw = (const float*)d_in[18];
    const float* t_pw  = (const float*)d_in[19];
    const float* t_pb  = (const float*)d_in[20];
    const float* t_ctw = (const float*)d_in[21];
    const float* t_ctb = (const float*)d_in[22];
    const float* qkv_w = (const float*)d_in[23];
    const float* qkv_b = (const float*)d_in[24];
    const float* ow    = (const float*)d_in[25];
    const float* ob    = (const float*)d_in[26];
    const float* upw0  = (const float*)d_in[27];
    const float* upb0  = (const float*)d_in[28];
    const float* upw1  = (const float*)d_in[29];
    const float* upb1  = (const float*)d_in[30];
    const float* fw    = (const float*)d_in[31];
    const float* fb    = (const float*)d_in[32];

    float* ws  = (float*)d_ws;
    float* out = (float*)d_out;

    // workspace layout (f32 units)
    float* ag    = ws + 0;          // 1,048,576
    float* x1    = ws + 1048576;    // 4,194,304
    float* Ureg  = ws + 5242880;    // 7,471,104 : u16 / Y / y1
    float* G     = ws + 12713984;   // 14,942,208 (later y0)
    float* h16f  = ws + 27656192;   // h bf16
    float* z16f  = ws + 29523968;   // z bf16
    float* wcatf = ws + 33259520;   // WcatT bf16
    float* wct2f = ws + 33521664;   // Wct2T bf16
    float* pwtf  = ws + 33652736;   // pwT bf16
    float* fout  = ws + 33718272;
    float* tout  = ws + 34766848;
    float* qkvbf = ws + 35815424;   // qkv bf16
    float* attnO = ws + 38961152;
    float* dp    = ws + 40009728;
    float* cw16f = ws + 41058304;
    float* fw16f = ws + 41066496;
    float* wup0f = ws + 41074688;
    float* wup1f = ws + 41082880;
    float* qkvwf = ws + 41091072;
    float* owtf  = ws + 41097216;
    float* wdw0f = ws + 41098240;   // down0 weights bf16 (36864 u16 = 18432 f32)
    float* wdw1f = ws + 41116672;   // down1 weights bf16
    ushort* u16    = (ushort*)Ureg;
    float*  Y      = Ureg;
    float*  y1     = Ureg;
    float*  y0     = G;
    ushort* h16    = (ushort*)h16f;
    ushort* z16    = (ushort*)z16f;
    ushort* WcatT  = (ushort*)wcatf;
    ushort* Wct2T  = (ushort*)wct2f;
    ushort* pwT    = (ushort*)pwtf;
    ushort* qkv16  = (ushort*)qkvbf;
    ushort* cw16   = (ushort*)cw16f;
    ushort* fw16   = (ushort*)fw16f;
    ushort* WupT0  = (ushort*)wup0f;
    ushort* WupT1  = (ushort*)wup1f;
    ushort* qkvwT  = (ushort*)qkvwf;
    ushort* owT    = (ushort*)owtf;
    ushort* WT9d0  = (ushort*)wdw0f;
    ushort* WT9d1  = (ushort*)wdw1f;
    float*  x0     = out;           // x0 parked in d_out

    dim3 blk(256);

    // weight packs
    pack_w16_k<<<dim3(64), blk, 0, stream>>>(cw, cw16, 16384);
    pack_w16_k<<<dim3(64), blk, 0, stream>>>(fw, fw16, 16384);
    pack_upw_k<<<dim3(64), blk, 0, stream>>>(upw0, WupT0);
    pack_upw_k<<<dim3(64), blk, 0, stream>>>(upw1, WupT1);
    pack_transposeT_k<<<dim3(48), blk, 0, stream>>>(qkv_w, qkvwT, 64, 192);
    pack_transposeT_k<<<dim3(16), blk, 0, stream>>>(ow, owT, 64, 64);
    pack_dw9_k<<<dim3(144), blk, 0, stream>>>(dw0, WT9d0);
    pack_dw9_k<<<dim3(144), blk, 0, stream>>>(dw1, WT9d1);

    // 1. compress (bf16 MFMA implicit GEMM over NCHW)
    mfma_nchw_k<64><<<dim3(256, 1, 8), blk, 0, stream>>>(A_in, cw16, cb, x0, 32768, 64, 256);

    // 2-3. downsample (implicit MFMA GEMM)
    down_mfma_k<<<dim3(1024), blk, 0, stream>>>(x0, WT9d0, db0, x1, TT, FF);
    down_mfma_k<<<dim3(256), blk, 0, stream>>>(x1, WT9d1, db1, ag, T2, F2);

    // ---- frequency pathway ----
    unfold_freq_k<<<dim3((MF * II) / 256), blk, 0, stream>>>(ag, u16);
    pack_wcatT_k<<<dim3(2048), blk, 0, stream>>>(f_Wx, f_Whw, WcatT);
    mfma_gemm_k<<<dim3(8, MF / 128), blk, 0, stream>>>(u16, WcatT, G, nullptr, nullptr,
        MF, 1024, 512, 0);
    sru_scan_k<<<dim3(131072 / 256), blk, 0, stream>>>(G, f_bf, f_br, h16, 512, LF);
    pack_pwT_k<<<dim3(512), blk, 0, stream>>>(f_pw, pwT);
    mfma_gemm_k<<<dim3(4, MF / 128), blk, 0, stream>>>(h16, pwT, nullptr, z16, f_pb,
        MF, 512, 256, 1);
    pack_wct2T_k<<<dim3(1024), blk, 0, stream>>>(f_ctw, Wct2T);
    mfma_gemm_k<<<dim3(4, MF / 128), blk, 0, stream>>>(z16, Wct2T, Y, nullptr, nullptr,
        MF, 512, 512, 0);
    convt_reduce_k<<<dim3(4096), blk, 0, stream>>>(Y, f_ctb, ag, fout, 64, LF, 32, 0);

    // ---- time pathway ----
    unfold_time_k<<<dim3((MT * II) / 256), blk, 0, stream>>>(ag, u16);
    pack_wcatT_k<<<dim3(2048), blk, 0, stream>>>(t_Wx, t_Whw, WcatT);
    mfma_gemm_k<<<dim3(8, MT / 128), blk, 0, stream>>>(u16, WcatT, G, nullptr, nullptr,
        MT, 1024, 512, 0);
    sru_scan_k<<<dim3(65536 / 256), blk, 0, stream>>>(G, t_bf, t_br, h16, 256, LT);
    pack_pwT_k<<<dim3(512), blk, 0, stream>>>(t_pw, pwT);
    mfma_gemm_k<<<dim3(4, MT / 128), blk, 0, stream>>>(h16, pwT, nullptr, z16, t_pb,
        MT, 512, 256, 1);
    pack_wct2T_k<<<dim3(1024), blk, 0, stream>>>(t_ctw, Wct2T);
    mfma_gemm_k<<<dim3(4, MT / 128), blk, 0, stream>>>(z16, Wct2T, Y, nullptr, nullptr,
        MT, 512, 512, 0);
    convt_reduce_k<<<dim3(4096), blk, 0, stream>>>(Y, t_ctb, fout, tout, 32, LT, 64, 1);

    // ---- attention ----
    mfma_qkv_k<<<dim3(16, 1, 8), blk, 0, stream>>>(tout, qkvwT, qkv_b, qkv16);
    attn_mfma_k<<<dim3(16, NHEADS, BB), blk, 0, stream>>>(qkv16, attnO);
    mfma_attnout_k<<<dim3(16, 1, 8), blk, 0, stream>>>(attnO, owT, ob, tout, dp);

    // ---- reconstruction (MFMA up-convs, fused bias+residual) ----
    up_mfma_k<<<dim3(16, 2, 8), blk, 0, stream>>>(dp, WupT0, upb0, x1, y1, 2048, 5);
    up_mfma_k<<<dim3(64, 2, 8), blk, 0, stream>>>(y1, WupT1, upb1, x0, y0, 8192, 6);

    // final 1x1 conv (bf16 MFMA implicit GEMM)
    mfma_nchw_k<128><<<dim3(256, 2, 8), blk, 0, stream>>>(y0, fw16, fb, out, 32768, 256, 64);
}